// Round 3
// baseline (182.757 us; speedup 1.0000x reference)
//
#include <hip/hip_runtime.h>

#define NTOK 2048
#define CDIM 1024
#define NHEAD 16
#define HDIM 64
#define NFRM 8
#define FTOK 256

typedef unsigned short ushort;
typedef unsigned long long u64;
typedef __attribute__((ext_vector_type(8))) short short8;     // 8 bf16 = 4 VGPRs (MFMA A/B frag)
typedef __attribute__((ext_vector_type(8))) ushort ushort8;
typedef __attribute__((ext_vector_type(4))) ushort ushort4v;
typedef __attribute__((ext_vector_type(4))) float floatx4;    // MFMA C/D frag

__device__ __forceinline__ ushort f2bf(float f) {
    unsigned int u = __float_as_uint(f);
    return (ushort)((u + 0x7fffu + ((u >> 16) & 1u)) >> 16);   // RNE
}

// async global->LDS, 16B per lane; LDS dest = wave-uniform base + lane*16
__device__ __forceinline__ void gload_lds16(const void* g, void* l) {
    __builtin_amdgcn_global_load_lds(
        (const __attribute__((address_space(1))) unsigned int*)(uintptr_t)g,
        (__attribute__((address_space(3))) unsigned int*)(unsigned int)(uintptr_t)l,
        16, 0, 0);
}

// ---------------------------------------------------------------------------
// Fused prep: [0,2048) x fp32->bf16 ; [2048,2816) Wqkv^T ; [2816,3072) Wproj^T
// [3072] hub bitmask
// ---------------------------------------------------------------------------
__global__ __launch_bounds__(256)
void prep_kernel(const float* __restrict__ x, ushort* __restrict__ xb,
                 const float* __restrict__ Wqkv, ushort* __restrict__ wqkvT,
                 const float* __restrict__ Wproj, ushort* __restrict__ wprojT,
                 const int* __restrict__ is_hub, u64* __restrict__ hubmask)
{
    __shared__ ushort LT[64][72];   // [n][k]
    const int b = blockIdx.x, t = threadIdx.x;

    if (b < 2048) {                 // convx: 2048 blocks x 256 float4
        int i = b * 256 + t;
        float4 f = ((const float4*)x)[i];
        ushort4v o = { f2bf(f.x), f2bf(f.y), f2bf(f.z), f2bf(f.w) };
        ((ushort4v*)xb)[i] = o;
        return;
    }
    if (b >= 3072) {                // hub bitmask: 32 tiles of 64 tokens
        if (t < NTOK / 64) {
            u64 m = 0;
            for (int j = 0; j < 64; ++j)
                m |= (u64)(is_hub[t * 64 + j] != 0) << j;
            hubmask[t] = m;
        }
        return;
    }

    const float* W; ushort* WT; int K, N, n0, k0;
    if (b < 2816) { int idx = b - 2048; W = Wqkv;  WT = wqkvT;  K = 1024; N = 3072;
                    n0 = (idx % 48) * 64; k0 = (idx / 48) * 64; }
    else          { int idx = b - 2816; W = Wproj; WT = wprojT; K = 1024; N = 1024;
                    n0 = (idx & 15) * 64; k0 = (idx >> 4) * 64; }

    const int kr = t >> 4, nc = t & 15;
#pragma unroll
    for (int i = 0; i < 4; ++i) {
        int k = kr + i * 16;
        float4 w4 = *(const float4*)(W + (size_t)(k0 + k) * N + n0 + nc * 4);
        LT[nc*4+0][k] = f2bf(w4.x);
        LT[nc*4+1][k] = f2bf(w4.y);
        LT[nc*4+2][k] = f2bf(w4.z);
        LT[nc*4+3][k] = f2bf(w4.w);
    }
    __syncthreads();
    const int n = t >> 2;
#pragma unroll
    for (int half = 0; half < 2; ++half) {
        int kc = (t & 3) + 4 * half;
        ushort8 v = *(const ushort8*)&LT[n][kc * 8];
        *(ushort8*)(WT + (size_t)(n0 + n) * K + k0 + kc * 8) = v;
    }
}

// ---------------------------------------------------------------------------
// bf16 MFMA GEMM: C = A[M,K] @ BT[N,K]^T + bias
// mode 0: fp32 store row-major [M][N]
// mode 1: QKV scatter — Q,K -> qkvb [2][H][N][D]; V -> vTb [H][D][N] (fused T)
// ---------------------------------------------------------------------------
__global__ __launch_bounds__(256)
void gemm_bt_kernel(const ushort* __restrict__ A, const ushort* __restrict__ BT,
                    const float* __restrict__ bias, void* __restrict__ out,
                    ushort* __restrict__ vtb,
                    int M, int N, int K, int mode)
{
    __shared__ ushort As[2][128 * 32];
    __shared__ ushort Bs[2][128 * 32];

    const int t = threadIdx.x;
    const int wave = t >> 6, lane = t & 63;
    const int quad = lane >> 4, l15 = lane & 15;
    const int row0 = blockIdx.y * 128, col0 = blockIdx.x * 128;
    const int wm = (wave >> 1) * 64, wn = (wave & 1) * 64;

    const int sr = lane >> 2;         // row within a 16-row staging group
    const int sc = (lane & 3) * 8;    // ushort offset (16B chunks)
    const int r0 = wave * 32;

    floatx4 acc[4][4];
#pragma unroll
    for (int i = 0; i < 4; ++i)
#pragma unroll
        for (int j = 0; j < 4; ++j) acc[i][j] = (floatx4){0.f, 0.f, 0.f, 0.f};

    gload_lds16(A  + (size_t)(row0 + r0      + sr) * K + sc, &As[0][ r0       * 32]);
    gload_lds16(A  + (size_t)(row0 + r0 + 16 + sr) * K + sc, &As[0][(r0 + 16) * 32]);
    gload_lds16(BT + (size_t)(col0 + r0      + sr) * K + sc, &Bs[0][ r0       * 32]);
    gload_lds16(BT + (size_t)(col0 + r0 + 16 + sr) * K + sc, &Bs[0][(r0 + 16) * 32]);

    const int nk = K >> 5;
    for (int ki = 0; ki < nk; ++ki) {
        __syncthreads();   // buf[ki&1] staged; all waves done reading buf[(ki+1)&1]
        if (ki + 1 < nk) {
            const int kn = (ki + 1) << 5;
            const int b = (ki + 1) & 1;
            gload_lds16(A  + (size_t)(row0 + r0      + sr) * K + kn + sc, &As[b][ r0       * 32]);
            gload_lds16(A  + (size_t)(row0 + r0 + 16 + sr) * K + kn + sc, &As[b][(r0 + 16) * 32]);
            gload_lds16(BT + (size_t)(col0 + r0      + sr) * K + kn + sc, &Bs[b][ r0       * 32]);
            gload_lds16(BT + (size_t)(col0 + r0 + 16 + sr) * K + kn + sc, &Bs[b][(r0 + 16) * 32]);
        }
        const ushort* as = As[ki & 1];
        const ushort* bs = Bs[ki & 1];

        short8 af[4], bfr[4];
#pragma unroll
        for (int i = 0; i < 4; ++i)
            af[i] = *(const short8*)&as[(wm + i * 16 + l15) * 32 + quad * 8];
#pragma unroll
        for (int j = 0; j < 4; ++j)
            bfr[j] = *(const short8*)&bs[(wn + j * 16 + l15) * 32 + quad * 8];
#pragma unroll
        for (int i = 0; i < 4; ++i)
#pragma unroll
            for (int j = 0; j < 4; ++j)
                acc[i][j] = __builtin_amdgcn_mfma_f32_16x16x32_bf16(af[i], bfr[j], acc[i][j], 0, 0, 0);
    }

    if (mode == 0) {
        float* outf = (float*)out;
#pragma unroll
        for (int j = 0; j < 4; ++j) {
            int col = col0 + wn + j * 16 + l15;
            float bb = bias[col];
#pragma unroll
            for (int i = 0; i < 4; ++i) {
                int rowb = row0 + wm + i * 16 + quad * 4;
#pragma unroll
                for (int r = 0; r < 4; ++r)
                    outf[(size_t)(rowb + r) * N + col] = acc[i][j][r] + bb;
            }
        }
    } else {
        ushort* outb = (ushort*)out;
#pragma unroll
        for (int j = 0; j < 4; ++j) {
            int col = col0 + wn + j * 16 + l15;
            float bb = bias[col];
            int part = col >> 10, hh = (col >> 6) & 15, d = col & 63;
            if (part < 2) {        // Q,K -> [part][H][N][D]
                ushort* dst = outb + ((size_t)(part * NHEAD + hh) * NTOK) * HDIM + d;
#pragma unroll
                for (int i = 0; i < 4; ++i) {
                    int rowb = row0 + wm + i * 16 + quad * 4;
#pragma unroll
                    for (int r = 0; r < 4; ++r)
                        dst[(size_t)(rowb + r) * HDIM] = f2bf(acc[i][j][r] + bb);
                }
            } else {               // V -> vT [H][D][N] directly (fused transpose)
                ushort* dst = vtb + ((size_t)hh * HDIM + d) * NTOK;
#pragma unroll
                for (int i = 0; i < 4; ++i) {
                    int rowb = row0 + wm + i * 16 + quad * 4;
#pragma unroll
                    for (int r = 0; r < 4; ++r)
                        dst[rowb + r] = f2bf(acc[i][j][r] + bb);
                }
            }
        }
    }
}

// ---------------------------------------------------------------------------
// Split-K barrier-light MFMA flash attention.
// R2 diagnosis: R1 was latency-bound (MfmaUtil 3.4%, Occupancy 13.8%, HBM 2.4%)
// — direct-L2 frag loads with only 2 waves/SIMD exposed ~400cyc L2 latency.
// R2 fix: (a) 8 waves/block, wave pairs split the visible key-tile list by
// parity (no-max softmax => partials merge by plain addition; one LDS merge +
// one barrier at the end) -> 4096 waves = 4/SIMD (__launch_bounds__(512,4));
// (b) per tile, all 8 K-frag loads issue before the 8 V-frag loads, so the
// compiler's counted vmcnt lets QK wait only on K while V flies under softmax.
// K/V stay L2-resident (head-locked swizzle, 1.5MB/XCD).
// ---------------------------------------------------------------------------
__global__ __launch_bounds__(512, 4)
void attn_tile_kernel(const ushort* __restrict__ qkvb,   // [2][H][N][D] bf16 (Q,K)
                      const ushort* __restrict__ vTb,    // [H][D][N] bf16
                      const int* __restrict__ frame_ids,
                      const u64* __restrict__ hubmask,   // [NTOK/64]
                      const int* __restrict__ adj,
                      const float* __restrict__ frame_bias,
                      ushort* __restrict__ attnb)        // [N][C] bf16
{
    __shared__ ushort Ps[8][16 * 72];    // per-wave P strip (wave-private)
    __shared__ float  Om[4][64][21];     // merge: [wq][lane][16 O + 4 l], pad->21

    const int t = threadIdx.x;
    const int wave = t >> 6, lane = t & 63;
    const int wq = wave & 3, wk = wave >> 2;    // q sub-tile, key-list half
    const int quad = lane >> 4, l15 = lane & 15;
    const int b = blockIdx.x;
    const int h = b & 15, q0 = (b >> 4) * 64;   // XCD-locking swizzle

    const ushort* Qg = qkvb + ((size_t)h * NTOK) * HDIM;
    const ushort* Kg = qkvb + ((size_t)(NHEAD + h) * NTOK) * HDIM;
    const ushort* Vg = vTb + ((size_t)h * HDIM) * NTOK;

    // Q A-frags in registers (wave owns q rows q0 + wq*16 .. +16)
    short8 aq0 = *(const short8*)(Qg + (size_t)(q0 + wq * 16 + l15) * HDIM + quad * 8);
    short8 aq1 = *(const short8*)(Qg + (size_t)(q0 + wq * 16 + l15) * HDIM + 32 + quad * 8);

    // packed visible-frame list (uniform)
    const int fq = frame_ids[q0];
    unsigned vpack = 0; int nv = 0;
#pragma unroll
    for (int f = 0; f < NFRM; ++f)
        if (adj[fq * NFRM + f]) { vpack |= (unsigned)f << (3 * nv); ++nv; }

    const u64 hmq = hubmask[q0 >> 6];
    int qh[4];
#pragma unroll
    for (int r = 0; r < 4; ++r) qh[r] = (int)((hmq >> (wq * 16 + quad * 4 + r)) & 1);

    float lpart[4] = {0.f, 0.f, 0.f, 0.f};
    floatx4 oacc[4];
#pragma unroll
    for (int dt = 0; dt < 4; ++dt) oacc[dt] = (floatx4){0.f, 0.f, 0.f, 0.f};

    // this wave's tiles: vt = wk, wk+2, wk+4, ... (nv*2 of them; nv >= 1)
    const int nmine = nv * 2;
    int vt = wk;
    for (int j = 0; j < nmine; ++j, vt += 2) {
        const int fj = (int)((vpack >> (3 * (vt >> 2))) & 7u);
        const int k0 = fj * FTOK + (vt & 3) * 64;
        const float fb = frame_bias[fq * NFRM + fj];
        const bool same = (fj == fq);
        const u64 hmk = hubmask[k0 >> 6];

        // batched frag loads: K first, then V (counted vmcnt => QK waits K only)
        short8 kf[8], vf[8];
#pragma unroll
        for (int nt = 0; nt < 4; ++nt) {
            const ushort* kp = Kg + (size_t)(k0 + nt * 16 + l15) * HDIM + quad * 8;
            kf[2*nt]     = *(const short8*)kp;
            kf[2*nt + 1] = *(const short8*)(kp + 32);
        }
#pragma unroll
        for (int dt = 0; dt < 4; ++dt) {
            const ushort* vp = Vg + (size_t)(dt * 16 + l15) * NTOK + k0 + quad * 8;
            vf[2*dt]     = *(const short8*)vp;
            vf[2*dt + 1] = *(const short8*)(vp + 32);
        }

        // S strip [16 q][64 keys] = Q @ K^T
        floatx4 s[4];
#pragma unroll
        for (int nt = 0; nt < 4; ++nt) {
            s[nt] = (floatx4){0.f, 0.f, 0.f, 0.f};
            s[nt] = __builtin_amdgcn_mfma_f32_16x16x32_bf16(aq0, kf[2*nt],     s[nt], 0, 0, 0);
            s[nt] = __builtin_amdgcn_mfma_f32_16x16x32_bf16(aq1, kf[2*nt + 1], s[nt], 0, 0, 0);
        }

        // mask + scale + bias + exp (no max, no cross-lane); P -> LDS strip
#pragma unroll
        for (int r = 0; r < 4; ++r) {
            float ps = 0.f;
#pragma unroll
            for (int nt = 0; nt < 4; ++nt) {
                int kh = (int)((hmk >> (nt * 16 + l15)) & 1);
                bool allow = same || ((qh[r] == 0) && (kh == 0));
                float sv = allow ? fmaf(s[nt][r], 0.125f, fb) : -1.0e30f;
                float p = __expf(sv);          // exp(-1e30) = 0 exactly
                ps += p;
                Ps[wave][(quad * 4 + r) * 72 + nt * 16 + l15] = f2bf(p);
            }
            lpart[r] += ps;
        }

        // O strip += P @ V  (wave-private P strip; V frags already in flight)
        short8 ap0 = *(const short8*)&Ps[wave][l15 * 72 + quad * 8];
        short8 ap1 = *(const short8*)&Ps[wave][l15 * 72 + 32 + quad * 8];
#pragma unroll
        for (int dt = 0; dt < 4; ++dt) {
            oacc[dt] = __builtin_amdgcn_mfma_f32_16x16x32_bf16(ap0, vf[2*dt],     oacc[dt], 0, 0, 0);
            oacc[dt] = __builtin_amdgcn_mfma_f32_16x16x32_bf16(ap1, vf[2*dt + 1], oacc[dt], 0, 0, 0);
        }
    }

    // merge the two key-half partials (plain sums — no-max softmax)
    if (wk == 1) {
#pragma unroll
        for (int dt = 0; dt < 4; ++dt)
#pragma unroll
            for (int r = 0; r < 4; ++r) Om[wq][lane][dt * 4 + r] = oacc[dt][r];
#pragma unroll
        for (int r = 0; r < 4; ++r) Om[wq][lane][16 + r] = lpart[r];
    }
    __syncthreads();
    if (wk == 1) return;

#pragma unroll
    for (int dt = 0; dt < 4; ++dt)
#pragma unroll
        for (int r = 0; r < 4; ++r) oacc[dt][r] += Om[wq][lane][dt * 4 + r];
#pragma unroll
    for (int r = 0; r < 4; ++r) lpart[r] += Om[wq][lane][16 + r];

    // final row-sum reduction across the 16 l15 lanes
    float linv[4];
#pragma unroll
    for (int r = 0; r < 4; ++r) {
        float ls = lpart[r];
        ls += __shfl_xor(ls, 1);
        ls += __shfl_xor(ls, 2);
        ls += __shfl_xor(ls, 4);
        ls += __shfl_xor(ls, 8);
        linv[r] = 1.0f / ls;
    }

    // epilogue: attnb[row][h*64 + d] bf16
#pragma unroll
    for (int dt = 0; dt < 4; ++dt) {
        int col = h * HDIM + dt * 16 + l15;
#pragma unroll
        for (int r = 0; r < 4; ++r) {
            int row = q0 + wq * 16 + quad * 4 + r;
            attnb[(size_t)row * CDIM + col] = f2bf(oacc[dt][r] * linv[r]);
        }
    }
}

// ---------------------------------------------------------------------------
extern "C" void kernel_launch(void* const* d_in, const int* in_sizes, int n_in,
                              void* d_out, int out_size, void* d_ws, size_t ws_size,
                              hipStream_t stream)
{
    const float* x          = (const float*)d_in[0];
    const int*   frame_ids  = (const int*)d_in[1];
    const int*   is_hub     = (const int*)d_in[2];
    const int*   adj        = (const int*)d_in[3];
    const float* frame_bias = (const float*)d_in[4];
    const float* Wqkv       = (const float*)d_in[5];
    const float* bqkv       = (const float*)d_in[6];
    const float* Wproj      = (const float*)d_in[7];
    const float* bproj      = (const float*)d_in[8];
    float* out = (float*)d_out;

    // workspace layout (ushort units)
    ushort* xb     = (ushort*)d_ws;            // 2048*1024
    ushort* wqkvT  = xb     + 2097152;         // 3072*1024
    ushort* wprojT = wqkvT  + 3145728;         // 1024*1024
    ushort* qkvb   = wprojT + 1048576;         // [2][H][N][D] used
    ushort* vTb    = qkvb   + 6291456;         // 16*64*2048
    ushort* attnb  = vTb    + 2097152;         // 2048*1024
    u64*    hubmask = (u64*)(attnb + 2097152); // 32 x u64

    prep_kernel<<<dim3(3073), dim3(256), 0, stream>>>(
        x, xb, Wqkv, wqkvT, Wproj, wprojT, is_hub, hubmask);

    // QKV: [2048,1024] @ [1024,3072]; Q,K -> qkvb, V -> vTb (fused transpose)
    gemm_bt_kernel<<<dim3(3 * CDIM / 128, NTOK / 128), dim3(256), 0, stream>>>(
        xb, wqkvT, bqkv, qkvb, vTb, NTOK, 3 * CDIM, CDIM, 1);

    attn_tile_kernel<<<dim3(512), dim3(512), 0, stream>>>(
        qkvb, vTb, frame_ids, hubmask, adj, frame_bias, attnb);

    // proj: [2048,1024] @ [1024,1024] -> fp32 d_out
    gemm_bt_kernel<<<dim3(CDIM / 128, NTOK / 128), dim3(256), 0, stream>>>(
        attnb, wprojT, bproj, out, nullptr, NTOK, CDIM, CDIM, 0);
}

// Round 4
// 146.070 us; speedup vs baseline: 1.2512x; 1.2512x over previous
//
#include <hip/hip_runtime.h>

#define NTOK 2048
#define CDIM 1024
#define NHEAD 16
#define HDIM 64
#define NFRM 8
#define FTOK 256

typedef unsigned short ushort;
typedef unsigned long long u64;
typedef __attribute__((ext_vector_type(8))) short short8;     // 8 bf16 = 4 VGPRs (MFMA A/B frag)
typedef __attribute__((ext_vector_type(8))) ushort ushort8;
typedef __attribute__((ext_vector_type(4))) ushort ushort4v;
typedef __attribute__((ext_vector_type(4))) float floatx4;    // MFMA C/D frag

__device__ __forceinline__ ushort f2bf(float f) {
    unsigned int u = __float_as_uint(f);
    return (ushort)((u + 0x7fffu + ((u >> 16) & 1u)) >> 16);   // RNE
}

// async global->LDS, 16B per lane; LDS dest = wave-uniform base + lane*16
__device__ __forceinline__ void gload_lds16(const void* g, void* l) {
    __builtin_amdgcn_global_load_lds(
        (const __attribute__((address_space(1))) unsigned int*)(uintptr_t)g,
        (__attribute__((address_space(3))) unsigned int*)(unsigned int)(uintptr_t)l,
        16, 0, 0);
}

// ---------------------------------------------------------------------------
// Fused prep: [0,2048) x fp32->bf16 ; [2048,2816) Wqkv^T ; [2816,3072) Wproj^T
// [3072] hub bitmask
// ---------------------------------------------------------------------------
__global__ __launch_bounds__(256)
void prep_kernel(const float* __restrict__ x, ushort* __restrict__ xb,
                 const float* __restrict__ Wqkv, ushort* __restrict__ wqkvT,
                 const float* __restrict__ Wproj, ushort* __restrict__ wprojT,
                 const int* __restrict__ is_hub, u64* __restrict__ hubmask)
{
    __shared__ ushort LT[64][72];   // [n][k]
    const int b = blockIdx.x, t = threadIdx.x;

    if (b < 2048) {                 // convx: 2048 blocks x 256 float4
        int i = b * 256 + t;
        float4 f = ((const float4*)x)[i];
        ushort4v o = { f2bf(f.x), f2bf(f.y), f2bf(f.z), f2bf(f.w) };
        ((ushort4v*)xb)[i] = o;
        return;
    }
    if (b >= 3072) {                // hub bitmask: 32 tiles of 64 tokens
        if (t < NTOK / 64) {
            u64 m = 0;
            for (int j = 0; j < 64; ++j)
                m |= (u64)(is_hub[t * 64 + j] != 0) << j;
            hubmask[t] = m;
        }
        return;
    }

    const float* W; ushort* WT; int K, N, n0, k0;
    if (b < 2816) { int idx = b - 2048; W = Wqkv;  WT = wqkvT;  K = 1024; N = 3072;
                    n0 = (idx % 48) * 64; k0 = (idx / 48) * 64; }
    else          { int idx = b - 2816; W = Wproj; WT = wprojT; K = 1024; N = 1024;
                    n0 = (idx & 15) * 64; k0 = (idx >> 4) * 64; }

    const int kr = t >> 4, nc = t & 15;
#pragma unroll
    for (int i = 0; i < 4; ++i) {
        int k = kr + i * 16;
        float4 w4 = *(const float4*)(W + (size_t)(k0 + k) * N + n0 + nc * 4);
        LT[nc*4+0][k] = f2bf(w4.x);
        LT[nc*4+1][k] = f2bf(w4.y);
        LT[nc*4+2][k] = f2bf(w4.z);
        LT[nc*4+3][k] = f2bf(w4.w);
    }
    __syncthreads();
    const int n = t >> 2;
#pragma unroll
    for (int half = 0; half < 2; ++half) {
        int kc = (t & 3) + 4 * half;
        ushort8 v = *(const ushort8*)&LT[n][kc * 8];
        *(ushort8*)(WT + (size_t)(n0 + n) * K + k0 + kc * 8) = v;
    }
}

// ---------------------------------------------------------------------------
// bf16 MFMA GEMM: C = A[M,K] @ BT[N,K]^T + bias
// mode 0: fp32 store row-major [M][N]
// mode 1: QKV scatter into MFMA-FRAGMENT-ORDER layouts (R3):
//   Q,K -> qkvb[part][h][tile64][(nt*2+half)*64 + quad*16 + l15]*8 + elem
//          (frag chunk for (nt,half) = 64 lanes x 16B contiguous)
//   V   -> vtb [h][tile64][(dt*2+half)*64 + quad*16 + l15]*8 + elem
//   so every attn frag load is ONE coalesced 1KB wave read (base+lane*16).
// ---------------------------------------------------------------------------
__global__ __launch_bounds__(256)
void gemm_bt_kernel(const ushort* __restrict__ A, const ushort* __restrict__ BT,
                    const float* __restrict__ bias, void* __restrict__ out,
                    ushort* __restrict__ vtb,
                    int M, int N, int K, int mode)
{
    __shared__ ushort As[2][128 * 32];
    __shared__ ushort Bs[2][128 * 32];

    const int t = threadIdx.x;
    const int wave = t >> 6, lane = t & 63;
    const int quad = lane >> 4, l15 = lane & 15;
    const int row0 = blockIdx.y * 128, col0 = blockIdx.x * 128;
    const int wm = (wave >> 1) * 64, wn = (wave & 1) * 64;

    const int sr = lane >> 2;         // row within a 16-row staging group
    const int sc = (lane & 3) * 8;    // ushort offset (16B chunks)
    const int r0 = wave * 32;

    floatx4 acc[4][4];
#pragma unroll
    for (int i = 0; i < 4; ++i)
#pragma unroll
        for (int j = 0; j < 4; ++j) acc[i][j] = (floatx4){0.f, 0.f, 0.f, 0.f};

    gload_lds16(A  + (size_t)(row0 + r0      + sr) * K + sc, &As[0][ r0       * 32]);
    gload_lds16(A  + (size_t)(row0 + r0 + 16 + sr) * K + sc, &As[0][(r0 + 16) * 32]);
    gload_lds16(BT + (size_t)(col0 + r0      + sr) * K + sc, &Bs[0][ r0       * 32]);
    gload_lds16(BT + (size_t)(col0 + r0 + 16 + sr) * K + sc, &Bs[0][(r0 + 16) * 32]);

    const int nk = K >> 5;
    for (int ki = 0; ki < nk; ++ki) {
        __syncthreads();   // buf[ki&1] staged; all waves done reading buf[(ki+1)&1]
        if (ki + 1 < nk) {
            const int kn = (ki + 1) << 5;
            const int b = (ki + 1) & 1;
            gload_lds16(A  + (size_t)(row0 + r0      + sr) * K + kn + sc, &As[b][ r0       * 32]);
            gload_lds16(A  + (size_t)(row0 + r0 + 16 + sr) * K + kn + sc, &As[b][(r0 + 16) * 32]);
            gload_lds16(BT + (size_t)(col0 + r0      + sr) * K + kn + sc, &Bs[b][ r0       * 32]);
            gload_lds16(BT + (size_t)(col0 + r0 + 16 + sr) * K + kn + sc, &Bs[b][(r0 + 16) * 32]);
        }
        const ushort* as = As[ki & 1];
        const ushort* bs = Bs[ki & 1];

        short8 af[4], bfr[4];
#pragma unroll
        for (int i = 0; i < 4; ++i)
            af[i] = *(const short8*)&as[(wm + i * 16 + l15) * 32 + quad * 8];
#pragma unroll
        for (int j = 0; j < 4; ++j)
            bfr[j] = *(const short8*)&bs[(wn + j * 16 + l15) * 32 + quad * 8];
#pragma unroll
        for (int i = 0; i < 4; ++i)
#pragma unroll
            for (int j = 0; j < 4; ++j)
                acc[i][j] = __builtin_amdgcn_mfma_f32_16x16x32_bf16(af[i], bfr[j], acc[i][j], 0, 0, 0);
    }

    if (mode == 0) {
        float* outf = (float*)out;
#pragma unroll
        for (int j = 0; j < 4; ++j) {
            int col = col0 + wn + j * 16 + l15;
            float bb = bias[col];
#pragma unroll
            for (int i = 0; i < 4; ++i) {
                int rowb = row0 + wm + i * 16 + quad * 4;
#pragma unroll
                for (int r = 0; r < 4; ++r)
                    outf[(size_t)(rowb + r) * N + col] = acc[i][j][r] + bb;
            }
        }
    } else {
        ushort* outb = (ushort*)out;
#pragma unroll
        for (int j = 0; j < 4; ++j) {
            int col = col0 + wn + j * 16 + l15;
            float bb = bias[col];
            int part = col >> 10, hh = (col >> 6) & 15, d = col & 63;
            if (part < 2) {        // Q,K frag-order: half/quad_k/elem from d
                int half = d >> 5, qk = (d & 31) >> 3, elem = d & 7;
                ushort* base = outb + (size_t)(part * NHEAD + hh) * (NTOK * HDIM);
#pragma unroll
                for (int i = 0; i < 4; ++i) {
                    int rowb = row0 + wm + i * 16 + quad * 4;
#pragma unroll
                    for (int r = 0; r < 4; ++r) {
                        int tok = rowb + r;
                        int tile = tok >> 6, kk = tok & 63;
                        int nt = kk >> 4, lk = kk & 15;
                        base[(size_t)tile * 4096 + ((nt * 2 + half) * 64 + qk * 16 + lk) * 8 + elem]
                            = f2bf(acc[i][j][r] + bb);
                    }
                }
            } else {               // V frag-order: dt/l15v from d; half/quad_v/elem from token
                int dt = d >> 4, lv = d & 15;
                ushort* base = vtb + (size_t)hh * (NTOK * HDIM);
#pragma unroll
                for (int i = 0; i < 4; ++i) {
                    int rowb = row0 + wm + i * 16 + quad * 4;
                    int tile = rowb >> 6, kk = rowb & 63;
                    int half = kk >> 5, qv = (kk & 31) >> 3, elem = kk & 7;   // elem..elem+3
                    ushort4v pk = { f2bf(acc[i][j][0] + bb), f2bf(acc[i][j][1] + bb),
                                    f2bf(acc[i][j][2] + bb), f2bf(acc[i][j][3] + bb) };
                    *(ushort4v*)&base[(size_t)tile * 4096 + ((dt * 2 + half) * 64 + qv * 16 + lv) * 8 + elem] = pk;
                }
            }
        }
    }
}

// ---------------------------------------------------------------------------
// Split-K MFMA flash attention on FRAGMENT-ORDER Q/K/V (R3).
// R2/R3 diagnosis: doubling occupancy left dur flat at MfmaUtil 3.3% -> the
// wall is the vector-memory path: scattered frag gathers (16B/lane from 16
// rows = 16 L2 transactions/instr + per-lane 64b address VALU). Fix: Q/K/V are
// pre-swizzled by the QKV GEMM into frag-chunk order, so every frag load here
// is base + idx*1024 + lane*16 — one contiguous 1KB wave read, 8 sequential
// 128B transactions, immediate-offset addressing. 8 waves/block, key-list
// split by parity (no-max softmax => partials merge by addition at the end).
// ---------------------------------------------------------------------------
__global__ __launch_bounds__(512, 4)
void attn_tile_kernel(const ushort* __restrict__ qkvb,   // frag-order Q,K
                      const ushort* __restrict__ vTb,    // frag-order V
                      const int* __restrict__ frame_ids,
                      const u64* __restrict__ hubmask,   // [NTOK/64]
                      const int* __restrict__ adj,
                      const float* __restrict__ frame_bias,
                      ushort* __restrict__ attnb)        // [N][C] bf16
{
    __shared__ ushort Ps[8][16 * 72];    // per-wave P strip (wave-private)
    __shared__ float  Om[4][64][21];     // merge: [wq][lane][16 O + 4 l], pad->21

    const int t = threadIdx.x;
    const int wave = t >> 6, lane = t & 63;
    const int wq = wave & 3, wk = wave >> 2;    // q sub-tile, key-list half
    const int quad = lane >> 4, l15 = lane & 15;
    const int b = blockIdx.x;
    const int h = b & 15, q0 = (b >> 4) * 64;   // XCD-locking swizzle

    const ushort* Qh = qkvb + (size_t)h * (NTOK * HDIM);
    const ushort* Kh = qkvb + (size_t)(NHEAD + h) * (NTOK * HDIM);
    const ushort* Vh = vTb + (size_t)h * (NTOK * HDIM);

    // Q A-frags (frag-order: one coalesced 1KB read each)
    const ushort* qt = Qh + (size_t)(q0 >> 6) * 4096;
    short8 aq0 = *(const short8*)(qt + ((wq * 2 + 0) * 64 + lane) * 8);
    short8 aq1 = *(const short8*)(qt + ((wq * 2 + 1) * 64 + lane) * 8);

    // packed visible-frame list (uniform)
    const int fq = frame_ids[q0];
    unsigned vpack = 0; int nv = 0;
#pragma unroll
    for (int f = 0; f < NFRM; ++f)
        if (adj[fq * NFRM + f]) { vpack |= (unsigned)f << (3 * nv); ++nv; }

    const u64 hmq = hubmask[q0 >> 6];
    int qh[4];
#pragma unroll
    for (int r = 0; r < 4; ++r) qh[r] = (int)((hmq >> (wq * 16 + quad * 4 + r)) & 1);

    float lpart[4] = {0.f, 0.f, 0.f, 0.f};
    floatx4 oacc[4];
#pragma unroll
    for (int dt = 0; dt < 4; ++dt) oacc[dt] = (floatx4){0.f, 0.f, 0.f, 0.f};

    // this wave's tiles: vt = wk, wk+2, wk+4, ... (nv*2 of them; nv >= 1)
    const int nmine = nv * 2;
    int vt = wk;
    for (int j = 0; j < nmine; ++j, vt += 2) {
        const int fj = (int)((vpack >> (3 * (vt >> 2))) & 7u);
        const int k0 = fj * FTOK + (vt & 3) * 64;
        const float fb = frame_bias[fq * NFRM + fj];
        const bool same = (fj == fq);
        const u64 hmk = hubmask[k0 >> 6];

        // batched coalesced frag loads: K first, then V (counted vmcnt =>
        // QK waits only on K; V stays in flight under softmax)
        const ushort* kt = Kh + (size_t)(k0 >> 6) * 4096;
        const ushort* vtp = Vh + (size_t)(k0 >> 6) * 4096;
        short8 kf[8], vf[8];
#pragma unroll
        for (int idx = 0; idx < 8; ++idx)
            kf[idx] = *(const short8*)(kt + (idx * 64 + lane) * 8);
#pragma unroll
        for (int idx = 0; idx < 8; ++idx)
            vf[idx] = *(const short8*)(vtp + (idx * 64 + lane) * 8);

        // S strip [16 q][64 keys] = Q @ K^T
        floatx4 s[4];
#pragma unroll
        for (int nt = 0; nt < 4; ++nt) {
            s[nt] = (floatx4){0.f, 0.f, 0.f, 0.f};
            s[nt] = __builtin_amdgcn_mfma_f32_16x16x32_bf16(aq0, kf[2*nt],     s[nt], 0, 0, 0);
            s[nt] = __builtin_amdgcn_mfma_f32_16x16x32_bf16(aq1, kf[2*nt + 1], s[nt], 0, 0, 0);
        }

        // mask + scale + bias + exp (no max, no cross-lane); P -> LDS strip
#pragma unroll
        for (int r = 0; r < 4; ++r) {
            float ps = 0.f;
#pragma unroll
            for (int nt = 0; nt < 4; ++nt) {
                int kh = (int)((hmk >> (nt * 16 + l15)) & 1);
                bool allow = same || ((qh[r] == 0) && (kh == 0));
                float sv = allow ? fmaf(s[nt][r], 0.125f, fb) : -1.0e30f;
                float p = __expf(sv);          // exp(-1e30) = 0 exactly
                ps += p;
                Ps[wave][(quad * 4 + r) * 72 + nt * 16 + l15] = f2bf(p);
            }
            lpart[r] += ps;
        }

        // O strip += P @ V  (wave-private P strip; V frags already in flight)
        short8 ap0 = *(const short8*)&Ps[wave][l15 * 72 + quad * 8];
        short8 ap1 = *(const short8*)&Ps[wave][l15 * 72 + 32 + quad * 8];
#pragma unroll
        for (int dt = 0; dt < 4; ++dt) {
            oacc[dt] = __builtin_amdgcn_mfma_f32_16x16x32_bf16(ap0, vf[2*dt],     oacc[dt], 0, 0, 0);
            oacc[dt] = __builtin_amdgcn_mfma_f32_16x16x32_bf16(ap1, vf[2*dt + 1], oacc[dt], 0, 0, 0);
        }
    }

    // merge the two key-half partials (plain sums — no-max softmax)
    if (wk == 1) {
#pragma unroll
        for (int dt = 0; dt < 4; ++dt)
#pragma unroll
            for (int r = 0; r < 4; ++r) Om[wq][lane][dt * 4 + r] = oacc[dt][r];
#pragma unroll
        for (int r = 0; r < 4; ++r) Om[wq][lane][16 + r] = lpart[r];
    }
    __syncthreads();
    if (wk == 1) return;

#pragma unroll
    for (int dt = 0; dt < 4; ++dt)
#pragma unroll
        for (int r = 0; r < 4; ++r) oacc[dt][r] += Om[wq][lane][dt * 4 + r];
#pragma unroll
    for (int r = 0; r < 4; ++r) lpart[r] += Om[wq][lane][16 + r];

    // final row-sum reduction across the 16 l15 lanes
    float linv[4];
#pragma unroll
    for (int r = 0; r < 4; ++r) {
        float ls = lpart[r];
        ls += __shfl_xor(ls, 1);
        ls += __shfl_xor(ls, 2);
        ls += __shfl_xor(ls, 4);
        ls += __shfl_xor(ls, 8);
        linv[r] = 1.0f / ls;
    }

    // epilogue: attnb[row][h*64 + d] bf16
#pragma unroll
    for (int dt = 0; dt < 4; ++dt) {
        int col = h * HDIM + dt * 16 + l15;
#pragma unroll
        for (int r = 0; r < 4; ++r) {
            int row = q0 + wq * 16 + quad * 4 + r;
            attnb[(size_t)row * CDIM + col] = f2bf(oacc[dt][r] * linv[r]);
        }
    }
}

// ---------------------------------------------------------------------------
extern "C" void kernel_launch(void* const* d_in, const int* in_sizes, int n_in,
                              void* d_out, int out_size, void* d_ws, size_t ws_size,
                              hipStream_t stream)
{
    const float* x          = (const float*)d_in[0];
    const int*   frame_ids  = (const int*)d_in[1];
    const int*   is_hub     = (const int*)d_in[2];
    const int*   adj        = (const int*)d_in[3];
    const float* frame_bias = (const float*)d_in[4];
    const float* Wqkv       = (const float*)d_in[5];
    const float* bqkv       = (const float*)d_in[6];
    const float* Wproj      = (const float*)d_in[7];
    const float* bproj      = (const float*)d_in[8];
    float* out = (float*)d_out;

    // workspace layout (ushort units)
    ushort* xb     = (ushort*)d_ws;            // 2048*1024
    ushort* wqkvT  = xb     + 2097152;         // 3072*1024
    ushort* wprojT = wqkvT  + 3145728;         // 1024*1024
    ushort* qkvb   = wprojT + 1048576;         // [2][H][N][D] used (frag-order)
    ushort* vTb    = qkvb   + 6291456;         // 16*64*2048 (frag-order)
    ushort* attnb  = vTb    + 2097152;         // 2048*1024
    u64*    hubmask = (u64*)(attnb + 2097152); // 32 x u64

    prep_kernel<<<dim3(3073), dim3(256), 0, stream>>>(
        x, xb, Wqkv, wqkvT, Wproj, wprojT, is_hub, hubmask);

    // QKV: [2048,1024] @ [1024,3072]; Q,K,V -> frag-order layouts
    gemm_bt_kernel<<<dim3(3 * CDIM / 128, NTOK / 128), dim3(256), 0, stream>>>(
        xb, wqkvT, bqkv, qkvb, vTb, NTOK, 3 * CDIM, CDIM, 1);

    attn_tile_kernel<<<dim3(512), dim3(512), 0, stream>>>(
        qkvb, vTb, frame_ids, hubmask, adj, frame_bias, attnb);

    // proj: [2048,1024] @ [1024,1024] -> fp32 d_out
    gemm_bt_kernel<<<dim3(CDIM / 128, NTOK / 128), dim3(256), 0, stream>>>(
        attnb, wprojT, bproj, out, nullptr, NTOK, CDIM, CDIM, 0);
}

// Round 5
// 144.808 us; speedup vs baseline: 1.2621x; 1.0087x over previous
//
#include <hip/hip_runtime.h>

#define NTOK 2048
#define CDIM 1024
#define NHEAD 16
#define HDIM 64
#define NFRM 8
#define FTOK 256

typedef unsigned short ushort;
typedef unsigned long long u64;
typedef __attribute__((ext_vector_type(8))) short short8;     // 8 bf16 = 4 VGPRs (MFMA A/B frag)
typedef __attribute__((ext_vector_type(8))) ushort ushort8;
typedef __attribute__((ext_vector_type(4))) ushort ushort4v;
typedef __attribute__((ext_vector_type(4))) float floatx4;    // MFMA C/D frag

__device__ __forceinline__ ushort f2bf(float f) {
    unsigned int u = __float_as_uint(f);
    return (ushort)((u + 0x7fffu + ((u >> 16) & 1u)) >> 16);   // RNE
}

// async global->LDS, 16B per lane; LDS dest = wave-uniform base + lane*16
__device__ __forceinline__ void gload_lds16(const void* g, void* l) {
    __builtin_amdgcn_global_load_lds(
        (const __attribute__((address_space(1))) unsigned int*)(uintptr_t)g,
        (__attribute__((address_space(3))) unsigned int*)(unsigned int)(uintptr_t)l,
        16, 0, 0);
}

// ---------------------------------------------------------------------------
// Fused prep: [0,2048) x fp32->bf16 ; [2048,2816) Wqkv^T ; [2816,3072) Wproj^T
// [3072] hub bitmask
// ---------------------------------------------------------------------------
__global__ __launch_bounds__(256)
void prep_kernel(const float* __restrict__ x, ushort* __restrict__ xb,
                 const float* __restrict__ Wqkv, ushort* __restrict__ wqkvT,
                 const float* __restrict__ Wproj, ushort* __restrict__ wprojT,
                 const int* __restrict__ is_hub, u64* __restrict__ hubmask)
{
    __shared__ ushort LT[64][72];   // [n][k]
    const int b = blockIdx.x, t = threadIdx.x;

    if (b < 2048) {                 // convx: 2048 blocks x 256 float4
        int i = b * 256 + t;
        float4 f = ((const float4*)x)[i];
        ushort4v o = { f2bf(f.x), f2bf(f.y), f2bf(f.z), f2bf(f.w) };
        ((ushort4v*)xb)[i] = o;
        return;
    }
    if (b >= 3072) {                // hub bitmask: 32 tiles of 64 tokens
        if (t < NTOK / 64) {
            u64 m = 0;
            for (int j = 0; j < 64; ++j)
                m |= (u64)(is_hub[t * 64 + j] != 0) << j;
            hubmask[t] = m;
        }
        return;
    }

    const float* W; ushort* WT; int K, N, n0, k0;
    if (b < 2816) { int idx = b - 2048; W = Wqkv;  WT = wqkvT;  K = 1024; N = 3072;
                    n0 = (idx % 48) * 64; k0 = (idx / 48) * 64; }
    else          { int idx = b - 2816; W = Wproj; WT = wprojT; K = 1024; N = 1024;
                    n0 = (idx & 15) * 64; k0 = (idx >> 4) * 64; }

    const int kr = t >> 4, nc = t & 15;
#pragma unroll
    for (int i = 0; i < 4; ++i) {
        int k = kr + i * 16;
        float4 w4 = *(const float4*)(W + (size_t)(k0 + k) * N + n0 + nc * 4);
        LT[nc*4+0][k] = f2bf(w4.x);
        LT[nc*4+1][k] = f2bf(w4.y);
        LT[nc*4+2][k] = f2bf(w4.z);
        LT[nc*4+3][k] = f2bf(w4.w);
    }
    __syncthreads();
    const int n = t >> 2;
#pragma unroll
    for (int half = 0; half < 2; ++half) {
        int kc = (t & 3) + 4 * half;
        ushort8 v = *(const ushort8*)&LT[n][kc * 8];
        *(ushort8*)(WT + (size_t)(n0 + n) * K + k0 + kc * 8) = v;
    }
}

// ---------------------------------------------------------------------------
// bf16 MFMA GEMM: C = A[M,K] @ BT[N,K]^T + bias.  BM=64, BN=128 (R4):
// grid quantization — QKV 24x32=768 blocks (3/CU exact), proj 8x32=256 (1/CU
// exact); previous 128x128 gave 384 (1.5 rounds) and 128 (half chip idle).
// Smaller acc (8 frags) + 24KB LDS -> more co-resident blocks hide the
// barrier drain. 4 waves in 2x2, each 32 rows x 64 cols.
// mode 0: fp32 store row-major [M][N]
// mode 1: QKV scatter into MFMA-FRAGMENT-ORDER layouts (R3):
//   Q,K -> qkvb[part][h][tile64][(nt*2+half)*64 + quad*16 + l15]*8 + elem
//   V   -> vtb [h][tile64][(dt*2+half)*64 + quad*16 + l15]*8 + elem
//   so every attn frag load is ONE coalesced 1KB wave read (base+lane*16).
// ---------------------------------------------------------------------------
__global__ __launch_bounds__(256)
void gemm_bt_kernel(const ushort* __restrict__ A, const ushort* __restrict__ BT,
                    const float* __restrict__ bias, void* __restrict__ out,
                    ushort* __restrict__ vtb,
                    int M, int N, int K, int mode)
{
    __shared__ ushort As[2][64 * 32];
    __shared__ ushort Bs[2][128 * 32];

    const int t = threadIdx.x;
    const int wave = t >> 6, lane = t & 63;
    const int quad = lane >> 4, l15 = lane & 15;
    const int row0 = blockIdx.y * 64, col0 = blockIdx.x * 128;
    const int wm = (wave >> 1) * 32, wn = (wave & 1) * 64;

    const int sr = lane >> 2;         // row within a 16-row staging group
    const int sc = (lane & 3) * 8;    // ushort offset (16B chunks)
    const int ra = wave * 16;         // A rows staged by this wave
    const int rb = wave * 32;         // B rows staged by this wave

    floatx4 acc[2][4];
#pragma unroll
    for (int i = 0; i < 2; ++i)
#pragma unroll
        for (int j = 0; j < 4; ++j) acc[i][j] = (floatx4){0.f, 0.f, 0.f, 0.f};

    gload_lds16(A  + (size_t)(row0 + ra      + sr) * K + sc, &As[0][ ra       * 32]);
    gload_lds16(BT + (size_t)(col0 + rb      + sr) * K + sc, &Bs[0][ rb       * 32]);
    gload_lds16(BT + (size_t)(col0 + rb + 16 + sr) * K + sc, &Bs[0][(rb + 16) * 32]);

    const int nk = K >> 5;
    for (int ki = 0; ki < nk; ++ki) {
        __syncthreads();   // buf[ki&1] staged; all waves done reading buf[(ki+1)&1]
        if (ki + 1 < nk) {
            const int kn = (ki + 1) << 5;
            const int b = (ki + 1) & 1;
            gload_lds16(A  + (size_t)(row0 + ra      + sr) * K + kn + sc, &As[b][ ra       * 32]);
            gload_lds16(BT + (size_t)(col0 + rb      + sr) * K + kn + sc, &Bs[b][ rb       * 32]);
            gload_lds16(BT + (size_t)(col0 + rb + 16 + sr) * K + kn + sc, &Bs[b][(rb + 16) * 32]);
        }
        const ushort* as = As[ki & 1];
        const ushort* bs = Bs[ki & 1];

        short8 af[2], bfr[4];
#pragma unroll
        for (int i = 0; i < 2; ++i)
            af[i] = *(const short8*)&as[(wm + i * 16 + l15) * 32 + quad * 8];
#pragma unroll
        for (int j = 0; j < 4; ++j)
            bfr[j] = *(const short8*)&bs[(wn + j * 16 + l15) * 32 + quad * 8];
#pragma unroll
        for (int i = 0; i < 2; ++i)
#pragma unroll
            for (int j = 0; j < 4; ++j)
                acc[i][j] = __builtin_amdgcn_mfma_f32_16x16x32_bf16(af[i], bfr[j], acc[i][j], 0, 0, 0);
    }

    if (mode == 0) {
        float* outf = (float*)out;
#pragma unroll
        for (int j = 0; j < 4; ++j) {
            int col = col0 + wn + j * 16 + l15;
            float bb = bias[col];
#pragma unroll
            for (int i = 0; i < 2; ++i) {
                int rowb = row0 + wm + i * 16 + quad * 4;
#pragma unroll
                for (int r = 0; r < 4; ++r)
                    outf[(size_t)(rowb + r) * N + col] = acc[i][j][r] + bb;
            }
        }
    } else {
        ushort* outb = (ushort*)out;
#pragma unroll
        for (int j = 0; j < 4; ++j) {
            int col = col0 + wn + j * 16 + l15;
            float bb = bias[col];
            int part = col >> 10, hh = (col >> 6) & 15, d = col & 63;
            if (part < 2) {        // Q,K frag-order: half/quad_k/elem from d
                int half = d >> 5, qk = (d & 31) >> 3, elem = d & 7;
                ushort* base = outb + (size_t)(part * NHEAD + hh) * (NTOK * HDIM);
#pragma unroll
                for (int i = 0; i < 2; ++i) {
                    int rowb = row0 + wm + i * 16 + quad * 4;
#pragma unroll
                    for (int r = 0; r < 4; ++r) {
                        int tok = rowb + r;
                        int tile = tok >> 6, kk = tok & 63;
                        int nt = kk >> 4, lk = kk & 15;
                        base[(size_t)tile * 4096 + ((nt * 2 + half) * 64 + qk * 16 + lk) * 8 + elem]
                            = f2bf(acc[i][j][r] + bb);
                    }
                }
            } else {               // V frag-order: dt/l15v from d; half/quad_v/elem from token
                int dt = d >> 4, lv = d & 15;
                ushort* base = vtb + (size_t)hh * (NTOK * HDIM);
#pragma unroll
                for (int i = 0; i < 2; ++i) {
                    int rowb = row0 + wm + i * 16 + quad * 4;
                    int tile = rowb >> 6, kk = rowb & 63;
                    int half = kk >> 5, qv = (kk & 31) >> 3, elem = kk & 7;   // elem..elem+3
                    ushort4v pk = { f2bf(acc[i][j][0] + bb), f2bf(acc[i][j][1] + bb),
                                    f2bf(acc[i][j][2] + bb), f2bf(acc[i][j][3] + bb) };
                    *(ushort4v*)&base[(size_t)tile * 4096 + ((dt * 2 + half) * 64 + qv * 16 + lv) * 8 + elem] = pk;
                }
            }
        }
    }
}

// ---------------------------------------------------------------------------
// Split-K MFMA flash attention on FRAGMENT-ORDER Q/K/V (R3, unchanged in R4).
// Every frag load is base + idx*1024 + lane*16 — one contiguous 1KB wave read.
// 8 waves/block, key-list split by parity (no-max softmax => partials merge
// by addition at the end). K/V L2-resident via head-locked swizzle.
// ---------------------------------------------------------------------------
__global__ __launch_bounds__(512, 4)
void attn_tile_kernel(const ushort* __restrict__ qkvb,   // frag-order Q,K
                      const ushort* __restrict__ vTb,    // frag-order V
                      const int* __restrict__ frame_ids,
                      const u64* __restrict__ hubmask,   // [NTOK/64]
                      const int* __restrict__ adj,
                      const float* __restrict__ frame_bias,
                      ushort* __restrict__ attnb)        // [N][C] bf16
{
    __shared__ ushort Ps[8][16 * 72];    // per-wave P strip (wave-private)
    __shared__ float  Om[4][64][21];     // merge: [wq][lane][16 O + 4 l], pad->21

    const int t = threadIdx.x;
    const int wave = t >> 6, lane = t & 63;
    const int wq = wave & 3, wk = wave >> 2;    // q sub-tile, key-list half
    const int quad = lane >> 4, l15 = lane & 15;
    const int b = blockIdx.x;
    const int h = b & 15, q0 = (b >> 4) * 64;   // XCD-locking swizzle

    const ushort* Qh = qkvb + (size_t)h * (NTOK * HDIM);
    const ushort* Kh = qkvb + (size_t)(NHEAD + h) * (NTOK * HDIM);
    const ushort* Vh = vTb + (size_t)h * (NTOK * HDIM);

    // Q A-frags (frag-order: one coalesced 1KB read each)
    const ushort* qt = Qh + (size_t)(q0 >> 6) * 4096;
    short8 aq0 = *(const short8*)(qt + ((wq * 2 + 0) * 64 + lane) * 8);
    short8 aq1 = *(const short8*)(qt + ((wq * 2 + 1) * 64 + lane) * 8);

    // packed visible-frame list (uniform)
    const int fq = frame_ids[q0];
    unsigned vpack = 0; int nv = 0;
#pragma unroll
    for (int f = 0; f < NFRM; ++f)
        if (adj[fq * NFRM + f]) { vpack |= (unsigned)f << (3 * nv); ++nv; }

    const u64 hmq = hubmask[q0 >> 6];
    int qh[4];
#pragma unroll
    for (int r = 0; r < 4; ++r) qh[r] = (int)((hmq >> (wq * 16 + quad * 4 + r)) & 1);

    float lpart[4] = {0.f, 0.f, 0.f, 0.f};
    floatx4 oacc[4];
#pragma unroll
    for (int dt = 0; dt < 4; ++dt) oacc[dt] = (floatx4){0.f, 0.f, 0.f, 0.f};

    // this wave's tiles: vt = wk, wk+2, wk+4, ... (nv*2 of them; nv >= 1)
    const int nmine = nv * 2;
    int vt = wk;
    for (int j = 0; j < nmine; ++j, vt += 2) {
        const int fj = (int)((vpack >> (3 * (vt >> 2))) & 7u);
        const int k0 = fj * FTOK + (vt & 3) * 64;
        const float fb = frame_bias[fq * NFRM + fj];
        const bool same = (fj == fq);
        const u64 hmk = hubmask[k0 >> 6];

        // batched coalesced frag loads: K first, then V (counted vmcnt =>
        // QK waits only on K; V stays in flight under softmax)
        const ushort* kt = Kh + (size_t)(k0 >> 6) * 4096;
        const ushort* vtp = Vh + (size_t)(k0 >> 6) * 4096;
        short8 kf[8], vf[8];
#pragma unroll
        for (int idx = 0; idx < 8; ++idx)
            kf[idx] = *(const short8*)(kt + (idx * 64 + lane) * 8);
#pragma unroll
        for (int idx = 0; idx < 8; ++idx)
            vf[idx] = *(const short8*)(vtp + (idx * 64 + lane) * 8);

        // S strip [16 q][64 keys] = Q @ K^T
        floatx4 s[4];
#pragma unroll
        for (int nt = 0; nt < 4; ++nt) {
            s[nt] = (floatx4){0.f, 0.f, 0.f, 0.f};
            s[nt] = __builtin_amdgcn_mfma_f32_16x16x32_bf16(aq0, kf[2*nt],     s[nt], 0, 0, 0);
            s[nt] = __builtin_amdgcn_mfma_f32_16x16x32_bf16(aq1, kf[2*nt + 1], s[nt], 0, 0, 0);
        }

        // mask + scale + bias + exp (no max, no cross-lane); P -> LDS strip
#pragma unroll
        for (int r = 0; r < 4; ++r) {
            float ps = 0.f;
#pragma unroll
            for (int nt = 0; nt < 4; ++nt) {
                int kh = (int)((hmk >> (nt * 16 + l15)) & 1);
                bool allow = same || ((qh[r] == 0) && (kh == 0));
                float sv = allow ? fmaf(s[nt][r], 0.125f, fb) : -1.0e30f;
                float p = __expf(sv);          // exp(-1e30) = 0 exactly
                ps += p;
                Ps[wave][(quad * 4 + r) * 72 + nt * 16 + l15] = f2bf(p);
            }
            lpart[r] += ps;
        }

        // O strip += P @ V  (wave-private P strip; V frags already in flight)
        short8 ap0 = *(const short8*)&Ps[wave][l15 * 72 + quad * 8];
        short8 ap1 = *(const short8*)&Ps[wave][l15 * 72 + 32 + quad * 8];
#pragma unroll
        for (int dt = 0; dt < 4; ++dt) {
            oacc[dt] = __builtin_amdgcn_mfma_f32_16x16x32_bf16(ap0, vf[2*dt],     oacc[dt], 0, 0, 0);
            oacc[dt] = __builtin_amdgcn_mfma_f32_16x16x32_bf16(ap1, vf[2*dt + 1], oacc[dt], 0, 0, 0);
        }
    }

    // merge the two key-half partials (plain sums — no-max softmax)
    if (wk == 1) {
#pragma unroll
        for (int dt = 0; dt < 4; ++dt)
#pragma unroll
            for (int r = 0; r < 4; ++r) Om[wq][lane][dt * 4 + r] = oacc[dt][r];
#pragma unroll
        for (int r = 0; r < 4; ++r) Om[wq][lane][16 + r] = lpart[r];
    }
    __syncthreads();
    if (wk == 1) return;

#pragma unroll
    for (int dt = 0; dt < 4; ++dt)
#pragma unroll
        for (int r = 0; r < 4; ++r) oacc[dt][r] += Om[wq][lane][dt * 4 + r];
#pragma unroll
    for (int r = 0; r < 4; ++r) lpart[r] += Om[wq][lane][16 + r];

    // final row-sum reduction across the 16 l15 lanes
    float linv[4];
#pragma unroll
    for (int r = 0; r < 4; ++r) {
        float ls = lpart[r];
        ls += __shfl_xor(ls, 1);
        ls += __shfl_xor(ls, 2);
        ls += __shfl_xor(ls, 4);
        ls += __shfl_xor(ls, 8);
        linv[r] = 1.0f / ls;
    }

    // epilogue: attnb[row][h*64 + d] bf16
#pragma unroll
    for (int dt = 0; dt < 4; ++dt) {
        int col = h * HDIM + dt * 16 + l15;
#pragma unroll
        for (int r = 0; r < 4; ++r) {
            int row = q0 + wq * 16 + quad * 4 + r;
            attnb[(size_t)row * CDIM + col] = f2bf(oacc[dt][r] * linv[r]);
        }
    }
}

// ---------------------------------------------------------------------------
extern "C" void kernel_launch(void* const* d_in, const int* in_sizes, int n_in,
                              void* d_out, int out_size, void* d_ws, size_t ws_size,
                              hipStream_t stream)
{
    const float* x          = (const float*)d_in[0];
    const int*   frame_ids  = (const int*)d_in[1];
    const int*   is_hub     = (const int*)d_in[2];
    const int*   adj        = (const int*)d_in[3];
    const float* frame_bias = (const float*)d_in[4];
    const float* Wqkv       = (const float*)d_in[5];
    const float* bqkv       = (const float*)d_in[6];
    const float* Wproj      = (const float*)d_in[7];
    const float* bproj      = (const float*)d_in[8];
    float* out = (float*)d_out;

    // workspace layout (ushort units)
    ushort* xb     = (ushort*)d_ws;            // 2048*1024
    ushort* wqkvT  = xb     + 2097152;         // 3072*1024
    ushort* wprojT = wqkvT  + 3145728;         // 1024*1024
    ushort* qkvb   = wprojT + 1048576;         // [2][H][N][D] used (frag-order)
    ushort* vTb    = qkvb   + 6291456;         // 16*64*2048 (frag-order)
    ushort* attnb  = vTb    + 2097152;         // 2048*1024
    u64*    hubmask = (u64*)(attnb + 2097152); // 32 x u64

    prep_kernel<<<dim3(3073), dim3(256), 0, stream>>>(
        x, xb, Wqkv, wqkvT, Wproj, wprojT, is_hub, hubmask);

    // QKV: [2048,1024] @ [1024,3072]; Q,K,V -> frag-order layouts
    gemm_bt_kernel<<<dim3(3 * CDIM / 128, NTOK / 64), dim3(256), 0, stream>>>(
        xb, wqkvT, bqkv, qkvb, vTb, NTOK, 3 * CDIM, CDIM, 1);

    attn_tile_kernel<<<dim3(512), dim3(512), 0, stream>>>(
        qkvb, vTb, frame_ids, hubmask, adj, frame_bias, attnb);

    // proj: [2048,1024] @ [1024,1024] -> fp32 d_out
    gemm_bt_kernel<<<dim3(CDIM / 128, NTOK / 64), dim3(256), 0, stream>>>(
        attnb, wprojT, bproj, out, nullptr, NTOK, CDIM, CDIM, 0);
}

// Round 7
// 142.663 us; speedup vs baseline: 1.2810x; 1.0150x over previous
//
#include <hip/hip_runtime.h>

#define NTOK 2048
#define CDIM 1024
#define NHEAD 16
#define HDIM 64
#define NFRM 8
#define FTOK 256

typedef unsigned short ushort;
typedef unsigned long long u64;
typedef __attribute__((ext_vector_type(8))) short short8;     // 8 bf16 = 4 VGPRs (MFMA A/B frag)
typedef __attribute__((ext_vector_type(8))) ushort ushort8;
typedef __attribute__((ext_vector_type(4))) ushort ushort4v;
typedef __attribute__((ext_vector_type(4))) float floatx4;    // MFMA C/D frag

__device__ __forceinline__ ushort f2bf(float f) {
    unsigned int u = __float_as_uint(f);
    return (ushort)((u + 0x7fffu + ((u >> 16) & 1u)) >> 16);   // RNE
}

// async global->LDS, 16B per lane; LDS dest = wave-uniform base + lane*16
__device__ __forceinline__ void gload_lds16(const void* g, void* l) {
    __builtin_amdgcn_global_load_lds(
        (const __attribute__((address_space(1))) unsigned int*)(uintptr_t)g,
        (__attribute__((address_space(3))) unsigned int*)(unsigned int)(uintptr_t)l,
        16, 0, 0);
}

// ---------------------------------------------------------------------------
// Fused prep: [0,2048) x fp32->bf16 ; [2048,2816) Wqkv^T ; [2816,3072) Wproj^T
// [3072] hub bitmask
// ---------------------------------------------------------------------------
__global__ __launch_bounds__(256)
void prep_kernel(const float* __restrict__ x, ushort* __restrict__ xb,
                 const float* __restrict__ Wqkv, ushort* __restrict__ wqkvT,
                 const float* __restrict__ Wproj, ushort* __restrict__ wprojT,
                 const int* __restrict__ is_hub, u64* __restrict__ hubmask)
{
    __shared__ ushort LT[64][72];   // [n][k]
    const int b = blockIdx.x, t = threadIdx.x;

    if (b < 2048) {                 // convx: 2048 blocks x 256 float4
        int i = b * 256 + t;
        float4 f = ((const float4*)x)[i];
        ushort4v o = { f2bf(f.x), f2bf(f.y), f2bf(f.z), f2bf(f.w) };
        ((ushort4v*)xb)[i] = o;
        return;
    }
    if (b >= 3072) {                // hub bitmask: 32 tiles of 64 tokens
        if (t < NTOK / 64) {
            u64 m = 0;
            for (int j = 0; j < 64; ++j)
                m |= (u64)(is_hub[t * 64 + j] != 0) << j;
            hubmask[t] = m;
        }
        return;
    }

    const float* W; ushort* WT; int K, N, n0, k0;
    if (b < 2816) { int idx = b - 2048; W = Wqkv;  WT = wqkvT;  K = 1024; N = 3072;
                    n0 = (idx % 48) * 64; k0 = (idx / 48) * 64; }
    else          { int idx = b - 2816; W = Wproj; WT = wprojT; K = 1024; N = 1024;
                    n0 = (idx & 15) * 64; k0 = (idx >> 4) * 64; }

    const int kr = t >> 4, nc = t & 15;
#pragma unroll
    for (int i = 0; i < 4; ++i) {
        int k = kr + i * 16;
        float4 w4 = *(const float4*)(W + (size_t)(k0 + k) * N + n0 + nc * 4);
        LT[nc*4+0][k] = f2bf(w4.x);
        LT[nc*4+1][k] = f2bf(w4.y);
        LT[nc*4+2][k] = f2bf(w4.z);
        LT[nc*4+3][k] = f2bf(w4.w);
    }
    __syncthreads();
    const int n = t >> 2;
#pragma unroll
    for (int half = 0; half < 2; ++half) {
        int kc = (t & 3) + 4 * half;
        ushort8 v = *(const ushort8*)&LT[n][kc * 8];
        *(ushort8*)(WT + (size_t)(n0 + n) * K + k0 + kc * 8) = v;
    }
}

// ---------------------------------------------------------------------------
// bf16 MFMA GEMM: C = A[M,K] @ BT[N,K]^T + bias.  Template on BM (R5):
//   BM=128 for QKV — 16 MFMA/wave/K-step (m103 tile curve: 128-row tiles
//     ~2.7x the K-loop throughput of 64-row); 384 blocks all co-resident
//     in one round at 2 blocks/CU, so no quantization cliff.
//   BM=64 for proj — 128-tile grid would be 128 blocks on 256 CUs (half
//     chip idle); 64-tile gives 256 blocks, exactly 1/CU.
// mode 0: fp32 store row-major [M][N]
// mode 1: QKV scatter into MFMA-FRAGMENT-ORDER layouts (R3):
//   Q,K -> qkvb[part][h][tile64][(nt*2+half)*64 + quad*16 + l15]*8 + elem
//   V   -> vtb [h][tile64][(dt*2+half)*64 + quad*16 + l15]*8 + elem
//   so every attn frag load is ONE coalesced 1KB wave read (base+lane*16).
// ---------------------------------------------------------------------------
template<int BM>
__global__ __launch_bounds__(256)
void gemm_bt_kernel(const ushort* __restrict__ A, const ushort* __restrict__ BT,
                    const float* __restrict__ bias, void* __restrict__ out,
                    ushort* __restrict__ vtb,
                    int M, int N, int K, int mode)
{
    constexpr int MI = BM / 32;          // acc row-frags per wave (2x2 wave grid)
    __shared__ ushort As[2][BM * 32];
    __shared__ ushort Bs[2][128 * 32];

    const int t = threadIdx.x;
    const int wave = t >> 6, lane = t & 63;
    const int quad = lane >> 4, l15 = lane & 15;
    const int row0 = blockIdx.y * BM, col0 = blockIdx.x * 128;
    const int wm = (wave >> 1) * (BM / 2), wn = (wave & 1) * 64;

    const int sr = lane >> 2;         // row within a 16-row staging group
    const int sc = (lane & 3) * 8;    // ushort offset (16B chunks)
    const int ra = wave * (BM / 4);   // A rows staged by this wave
    const int rb = wave * 32;         // B rows staged by this wave

    floatx4 acc[MI][4];
#pragma unroll
    for (int i = 0; i < MI; ++i)
#pragma unroll
        for (int j = 0; j < 4; ++j) acc[i][j] = (floatx4){0.f, 0.f, 0.f, 0.f};

#pragma unroll
    for (int ii = 0; ii < BM / 64; ++ii)
        gload_lds16(A + (size_t)(row0 + ra + ii * 16 + sr) * K + sc, &As[0][(ra + ii * 16) * 32]);
    gload_lds16(BT + (size_t)(col0 + rb      + sr) * K + sc, &Bs[0][ rb       * 32]);
    gload_lds16(BT + (size_t)(col0 + rb + 16 + sr) * K + sc, &Bs[0][(rb + 16) * 32]);

    const int nk = K >> 5;
    for (int ki = 0; ki < nk; ++ki) {
        __syncthreads();   // buf[ki&1] staged; all waves done reading buf[(ki+1)&1]
        if (ki + 1 < nk) {
            const int kn = (ki + 1) << 5;
            const int b = (ki + 1) & 1;
#pragma unroll
            for (int ii = 0; ii < BM / 64; ++ii)
                gload_lds16(A + (size_t)(row0 + ra + ii * 16 + sr) * K + kn + sc, &As[b][(ra + ii * 16) * 32]);
            gload_lds16(BT + (size_t)(col0 + rb      + sr) * K + kn + sc, &Bs[b][ rb       * 32]);
            gload_lds16(BT + (size_t)(col0 + rb + 16 + sr) * K + kn + sc, &Bs[b][(rb + 16) * 32]);
        }
        const ushort* as = As[ki & 1];
        const ushort* bs = Bs[ki & 1];

        short8 af[MI], bfr[4];
#pragma unroll
        for (int i = 0; i < MI; ++i)
            af[i] = *(const short8*)&as[(wm + i * 16 + l15) * 32 + quad * 8];
#pragma unroll
        for (int j = 0; j < 4; ++j)
            bfr[j] = *(const short8*)&bs[(wn + j * 16 + l15) * 32 + quad * 8];
#pragma unroll
        for (int i = 0; i < MI; ++i)
#pragma unroll
            for (int j = 0; j < 4; ++j)
                acc[i][j] = __builtin_amdgcn_mfma_f32_16x16x32_bf16(af[i], bfr[j], acc[i][j], 0, 0, 0);
    }

    if (mode == 0) {
        float* outf = (float*)out;
#pragma unroll
        for (int j = 0; j < 4; ++j) {
            int col = col0 + wn + j * 16 + l15;
            float bb = bias[col];
#pragma unroll
            for (int i = 0; i < MI; ++i) {
                int rowb = row0 + wm + i * 16 + quad * 4;
#pragma unroll
                for (int r = 0; r < 4; ++r)
                    outf[(size_t)(rowb + r) * N + col] = acc[i][j][r] + bb;
            }
        }
    } else {
        ushort* outb = (ushort*)out;
#pragma unroll
        for (int j = 0; j < 4; ++j) {
            int col = col0 + wn + j * 16 + l15;
            float bb = bias[col];
            int part = col >> 10, hh = (col >> 6) & 15, d = col & 63;
            if (part < 2) {        // Q,K frag-order: half/quad_k/elem from d
                int half = d >> 5, qk = (d & 31) >> 3, elem = d & 7;
                ushort* base = outb + (size_t)(part * NHEAD + hh) * (NTOK * HDIM);
#pragma unroll
                for (int i = 0; i < MI; ++i) {
                    int rowb = row0 + wm + i * 16 + quad * 4;
#pragma unroll
                    for (int r = 0; r < 4; ++r) {
                        int tok = rowb + r;
                        int tile = tok >> 6, kk = tok & 63;
                        int nt = kk >> 4, lk = kk & 15;
                        base[(size_t)tile * 4096 + ((nt * 2 + half) * 64 + qk * 16 + lk) * 8 + elem]
                            = f2bf(acc[i][j][r] + bb);
                    }
                }
            } else {               // V frag-order: dt/l15v from d; half/quad_v/elem from token
                int dt = d >> 4, lv = d & 15;
                ushort* base = vtb + (size_t)hh * (NTOK * HDIM);
#pragma unroll
                for (int i = 0; i < MI; ++i) {
                    int rowb = row0 + wm + i * 16 + quad * 4;
                    int tile = rowb >> 6, kk = rowb & 63;
                    int half = kk >> 5, qv = (kk & 31) >> 3, elem = kk & 7;   // elem..elem+3
                    ushort4v pk = { f2bf(acc[i][j][0] + bb), f2bf(acc[i][j][1] + bb),
                                    f2bf(acc[i][j][2] + bb), f2bf(acc[i][j][3] + bb) };
                    *(ushort4v*)&base[(size_t)tile * 4096 + ((dt * 2 + half) * 64 + qv * 16 + lv) * 8 + elem] = pk;
                }
            }
        }
    }
}

// ---------------------------------------------------------------------------
// Split-K MFMA flash attention on FRAGMENT-ORDER Q/K/V (R3/R4), softmax VALU
// diet (R5/R6): exp(0.125*s + fb) computed as exp2(fma(s, 0.125*log2e,
// fb*log2e)) (1 fma + 1 v_exp); mask select replaced by multiply with {0,1}
// floats hoisted per tile (exact: e*0 == 0 == exp(-1e30)). P->bf16 via the
// scalar RNE helper (R6: __hip_bfloat162 bit_cast doesn't compile on this
// ROCm; m240 says compiler handles converts well anyway).
// ~15-17 -> ~10 VALU per score element; softmax was the dominant attn cost
// (R3: VALUBusy:MfmaUtil = 4:1).
// ---------------------------------------------------------------------------
__global__ __launch_bounds__(512, 4)
void attn_tile_kernel(const ushort* __restrict__ qkvb,   // frag-order Q,K
                      const ushort* __restrict__ vTb,    // frag-order V
                      const int* __restrict__ frame_ids,
                      const u64* __restrict__ hubmask,   // [NTOK/64]
                      const int* __restrict__ adj,
                      const float* __restrict__ frame_bias,
                      ushort* __restrict__ attnb)        // [N][C] bf16
{
    __shared__ ushort Ps[8][16 * 72];    // per-wave P strip (wave-private)
    __shared__ float  Om[4][64][21];     // merge: [wq][lane][16 O + 4 l], pad->21

    const int t = threadIdx.x;
    const int wave = t >> 6, lane = t & 63;
    const int wq = wave & 3, wk = wave >> 2;    // q sub-tile, key-list half
    const int quad = lane >> 4, l15 = lane & 15;
    const int b = blockIdx.x;
    const int h = b & 15, q0 = (b >> 4) * 64;   // XCD-locking swizzle

    const ushort* Qh = qkvb + (size_t)h * (NTOK * HDIM);
    const ushort* Kh = qkvb + (size_t)(NHEAD + h) * (NTOK * HDIM);
    const ushort* Vh = vTb + (size_t)h * (NTOK * HDIM);

    // Q A-frags (frag-order: one coalesced 1KB read each)
    const ushort* qt = Qh + (size_t)(q0 >> 6) * 4096;
    short8 aq0 = *(const short8*)(qt + ((wq * 2 + 0) * 64 + lane) * 8);
    short8 aq1 = *(const short8*)(qt + ((wq * 2 + 1) * 64 + lane) * 8);

    // packed visible-frame list (uniform)
    const int fq = frame_ids[q0];
    unsigned vpack = 0; int nv = 0;
#pragma unroll
    for (int f = 0; f < NFRM; ++f)
        if (adj[fq * NFRM + f]) { vpack |= (unsigned)f << (3 * nv); ++nv; }

    const u64 hmq = hubmask[q0 >> 6];
    int qh[4];
#pragma unroll
    for (int r = 0; r < 4; ++r) qh[r] = (int)((hmq >> (wq * 16 + quad * 4 + r)) & 1);

    float lpart[4] = {0.f, 0.f, 0.f, 0.f};
    floatx4 oacc[4];
#pragma unroll
    for (int dt = 0; dt < 4; ++dt) oacc[dt] = (floatx4){0.f, 0.f, 0.f, 0.f};

    const float C1 = 0.18033688011112042f;   // 0.125 * log2(e)
    const float L2E = 1.4426950408889634f;

    // this wave's tiles: vt = wk, wk+2, wk+4, ... (nv*2 of them; nv >= 1)
    const int nmine = nv * 2;
    int vt = wk;
    for (int j = 0; j < nmine; ++j, vt += 2) {
        const int fj = (int)((vpack >> (3 * (vt >> 2))) & 7u);
        const int k0 = fj * FTOK + (vt & 3) * 64;
        const float fbl = frame_bias[fq * NFRM + fj] * L2E;
        const bool same = (fj == fq);
        const u64 hmk = hubmask[k0 >> 6];

        // batched coalesced frag loads: K first, then V (counted vmcnt =>
        // QK waits only on K; V stays in flight under softmax)
        const ushort* kt = Kh + (size_t)(k0 >> 6) * 4096;
        const ushort* vtp = Vh + (size_t)(k0 >> 6) * 4096;
        short8 kf[8], vf[8];
#pragma unroll
        for (int idx = 0; idx < 8; ++idx)
            kf[idx] = *(const short8*)(kt + (idx * 64 + lane) * 8);
#pragma unroll
        for (int idx = 0; idx < 8; ++idx)
            vf[idx] = *(const short8*)(vtp + (idx * 64 + lane) * 8);

        // S strip [16 q][64 keys] = Q @ K^T
        floatx4 s[4];
#pragma unroll
        for (int nt = 0; nt < 4; ++nt) {
            s[nt] = (floatx4){0.f, 0.f, 0.f, 0.f};
            s[nt] = __builtin_amdgcn_mfma_f32_16x16x32_bf16(aq0, kf[2*nt],     s[nt], 0, 0, 0);
            s[nt] = __builtin_amdgcn_mfma_f32_16x16x32_bf16(aq1, kf[2*nt + 1], s[nt], 0, 0, 0);
        }

        // per-tile {0,1} mask floats (hoisted): allow = same || (!qh && !kh)
        float mkf[4];
#pragma unroll
        for (int nt = 0; nt < 4; ++nt) {
            int kb = (int)(((unsigned)(hmk >> (nt * 16)) >> l15) & 1u);
            mkf[nt] = (same || !kb) ? 1.f : 0.f;
        }
        float mrf[4];
#pragma unroll
        for (int r = 0; r < 4; ++r) mrf[r] = (same || !qh[r]) ? 1.f : 0.f;

        // p = exp2(fma(s, C1, fbl)) * mkf * mrf; bf16 -> LDS strip
#pragma unroll
        for (int r = 0; r < 4; ++r) {
            float ps = 0.f;
            ushort* prow = &Ps[wave][(quad * 4 + r) * 72 + l15];
#pragma unroll
            for (int nt = 0; nt < 4; ++nt) {
                float e = __builtin_amdgcn_exp2f(fmaf(s[nt][r], C1, fbl));
                float p = e * mkf[nt] * mrf[r];
                ps += p;
                prow[nt * 16] = f2bf(p);
            }
            lpart[r] += ps;
        }

        // O strip += P @ V  (wave-private P strip; V frags already in flight)
        short8 ap0 = *(const short8*)&Ps[wave][l15 * 72 + quad * 8];
        short8 ap1 = *(const short8*)&Ps[wave][l15 * 72 + 32 + quad * 8];
#pragma unroll
        for (int dt = 0; dt < 4; ++dt) {
            oacc[dt] = __builtin_amdgcn_mfma_f32_16x16x32_bf16(ap0, vf[2*dt],     oacc[dt], 0, 0, 0);
            oacc[dt] = __builtin_amdgcn_mfma_f32_16x16x32_bf16(ap1, vf[2*dt + 1], oacc[dt], 0, 0, 0);
        }
    }

    // merge the two key-half partials (plain sums — no-max softmax)
    if (wk == 1) {
#pragma unroll
        for (int dt = 0; dt < 4; ++dt)
#pragma unroll
            for (int r = 0; r < 4; ++r) Om[wq][lane][dt * 4 + r] = oacc[dt][r];
#pragma unroll
        for (int r = 0; r < 4; ++r) Om[wq][lane][16 + r] = lpart[r];
    }
    __syncthreads();
    if (wk == 1) return;

#pragma unroll
    for (int dt = 0; dt < 4; ++dt)
#pragma unroll
        for (int r = 0; r < 4; ++r) oacc[dt][r] += Om[wq][lane][dt * 4 + r];
#pragma unroll
    for (int r = 0; r < 4; ++r) lpart[r] += Om[wq][lane][16 + r];

    // final row-sum reduction across the 16 l15 lanes
    float linv[4];
#pragma unroll
    for (int r = 0; r < 4; ++r) {
        float ls = lpart[r];
        ls += __shfl_xor(ls, 1);
        ls += __shfl_xor(ls, 2);
        ls += __shfl_xor(ls, 4);
        ls += __shfl_xor(ls, 8);
        linv[r] = 1.0f / ls;
    }

    // epilogue: attnb[row][h*64 + d] bf16
#pragma unroll
    for (int dt = 0; dt < 4; ++dt) {
        int col = h * HDIM + dt * 16 + l15;
#pragma unroll
        for (int r = 0; r < 4; ++r) {
            int row = q0 + wq * 16 + quad * 4 + r;
            attnb[(size_t)row * CDIM + col] = f2bf(oacc[dt][r] * linv[r]);
        }
    }
}

// ---------------------------------------------------------------------------
extern "C" void kernel_launch(void* const* d_in, const int* in_sizes, int n_in,
                              void* d_out, int out_size, void* d_ws, size_t ws_size,
                              hipStream_t stream)
{
    const float* x          = (const float*)d_in[0];
    const int*   frame_ids  = (const int*)d_in[1];
    const int*   is_hub     = (const int*)d_in[2];
    const int*   adj        = (const int*)d_in[3];
    const float* frame_bias = (const float*)d_in[4];
    const float* Wqkv       = (const float*)d_in[5];
    const float* bqkv       = (const float*)d_in[6];
    const float* Wproj      = (const float*)d_in[7];
    const float* bproj      = (const float*)d_in[8];
    float* out = (float*)d_out;

    // workspace layout (ushort units)
    ushort* xb     = (ushort*)d_ws;            // 2048*1024
    ushort* wqkvT  = xb     + 2097152;         // 3072*1024
    ushort* wprojT = wqkvT  + 3145728;         // 1024*1024
    ushort* qkvb   = wprojT + 1048576;         // [2][H][N][D] used (frag-order)
    ushort* vTb    = qkvb   + 6291456;         // 16*64*2048 (frag-order)
    ushort* attnb  = vTb    + 2097152;         // 2048*1024
    u64*    hubmask = (u64*)(attnb + 2097152); // 32 x u64

    prep_kernel<<<dim3(3073), dim3(256), 0, stream>>>(
        x, xb, Wqkv, wqkvT, Wproj, wprojT, is_hub, hubmask);

    // QKV: [2048,1024] @ [1024,3072]; Q,K,V -> frag-order layouts. BM=128.
    gemm_bt_kernel<128><<<dim3(3 * CDIM / 128, NTOK / 128), dim3(256), 0, stream>>>(
        xb, wqkvT, bqkv, qkvb, vTb, NTOK, 3 * CDIM, CDIM, 1);

    attn_tile_kernel<<<dim3(512), dim3(512), 0, stream>>>(
        qkvb, vTb, frame_ids, hubmask, adj, frame_bias, attnb);

    // proj: [2048,1024] @ [1024,1024] -> fp32 d_out. BM=64 (256 blocks, 1/CU).
    gemm_bt_kernel<64><<<dim3(CDIM / 128, NTOK / 64), dim3(256), 0, stream>>>(
        attnb, wprojT, bproj, out, nullptr, NTOK, CDIM, CDIM, 0);
}

// Round 8
// 141.866 us; speedup vs baseline: 1.2882x; 1.0056x over previous
//
#include <hip/hip_runtime.h>

#define NTOK 2048
#define CDIM 1024
#define NHEAD 16
#define HDIM 64
#define NFRM 8
#define FTOK 256

typedef unsigned short ushort;
typedef unsigned long long u64;
typedef __attribute__((ext_vector_type(8))) short short8;     // 8 bf16 = 4 VGPRs (MFMA A/B frag)
typedef __attribute__((ext_vector_type(8))) ushort ushort8;
typedef __attribute__((ext_vector_type(4))) ushort ushort4v;
typedef __attribute__((ext_vector_type(4))) float floatx4;    // MFMA C/D frag

__device__ __forceinline__ ushort f2bf(float f) {
    unsigned int u = __float_as_uint(f);
    return (ushort)((u + 0x7fffu + ((u >> 16) & 1u)) >> 16);   // RNE
}

// packed f32x2 -> bf16x2 (RNE, identical to f2bf); no builtin on gfx950 (m240)
__device__ __forceinline__ unsigned int cvt_pk_bf16(float lo, float hi) {
    unsigned int r;
    asm volatile("v_cvt_pk_bf16_f32 %0, %1, %2" : "=v"(r) : "v"(lo), "v"(hi));
    return r;
}

// async global->LDS, 16B per lane; LDS dest = wave-uniform base + lane*16
__device__ __forceinline__ void gload_lds16(const void* g, void* l) {
    __builtin_amdgcn_global_load_lds(
        (const __attribute__((address_space(1))) unsigned int*)(uintptr_t)g,
        (__attribute__((address_space(3))) unsigned int*)(unsigned int)(uintptr_t)l,
        16, 0, 0);
}

// ---------------------------------------------------------------------------
// Fused prep: [0,2048) x fp32->bf16 ; [2048,2816) Wqkv^T ; [2816,3072) Wproj^T
// [3072] hub bitmask
// ---------------------------------------------------------------------------
__global__ __launch_bounds__(256)
void prep_kernel(const float* __restrict__ x, ushort* __restrict__ xb,
                 const float* __restrict__ Wqkv, ushort* __restrict__ wqkvT,
                 const float* __restrict__ Wproj, ushort* __restrict__ wprojT,
                 const int* __restrict__ is_hub, u64* __restrict__ hubmask)
{
    __shared__ ushort LT[64][72];   // [n][k]
    const int b = blockIdx.x, t = threadIdx.x;

    if (b < 2048) {                 // convx: 2048 blocks x 256 float4
        int i = b * 256 + t;
        float4 f = ((const float4*)x)[i];
        ushort4v o = { f2bf(f.x), f2bf(f.y), f2bf(f.z), f2bf(f.w) };
        ((ushort4v*)xb)[i] = o;
        return;
    }
    if (b >= 3072) {                // hub bitmask: 32 tiles of 64 tokens
        if (t < NTOK / 64) {
            u64 m = 0;
            for (int j = 0; j < 64; ++j)
                m |= (u64)(is_hub[t * 64 + j] != 0) << j;
            hubmask[t] = m;
        }
        return;
    }

    const float* W; ushort* WT; int K, N, n0, k0;
    if (b < 2816) { int idx = b - 2048; W = Wqkv;  WT = wqkvT;  K = 1024; N = 3072;
                    n0 = (idx % 48) * 64; k0 = (idx / 48) * 64; }
    else          { int idx = b - 2816; W = Wproj; WT = wprojT; K = 1024; N = 1024;
                    n0 = (idx & 15) * 64; k0 = (idx >> 4) * 64; }

    const int kr = t >> 4, nc = t & 15;
#pragma unroll
    for (int i = 0; i < 4; ++i) {
        int k = kr + i * 16;
        float4 w4 = *(const float4*)(W + (size_t)(k0 + k) * N + n0 + nc * 4);
        LT[nc*4+0][k] = f2bf(w4.x);
        LT[nc*4+1][k] = f2bf(w4.y);
        LT[nc*4+2][k] = f2bf(w4.z);
        LT[nc*4+3][k] = f2bf(w4.w);
    }
    __syncthreads();
    const int n = t >> 2;
#pragma unroll
    for (int half = 0; half < 2; ++half) {
        int kc = (t & 3) + 4 * half;
        ushort8 v = *(const ushort8*)&LT[n][kc * 8];
        *(ushort8*)(WT + (size_t)(n0 + n) * K + k0 + kc * 8) = v;
    }
}

// ---------------------------------------------------------------------------
// bf16 MFMA GEMM: C = A[M,K] @ BT[N,K]^T + bias.  Template on BM (R5):
//   BM=128 for QKV, BM=64 for proj (grid quantization).
// mode 0: fp32 store row-major [M][N]
// mode 1: QKV scatter into MFMA-FRAGMENT-ORDER layouts (R3):
//   Q,K -> qkvb[part][h][tile64][(nt*2+half)*64 + quad*16 + l15]*8 + elem
//   V   -> vtb [h][tile64][...]  with PERMUTED key slots (R7): token kk goes
//          to slot g(kk) = (kk&15)*4 + (kk>>4). P's LDS layout in attn uses
//          the same g on its key index, so PV contracts consistently while
//          each attn lane's 4 P values become 4 CONSECUTIVE ushorts
//          (enables cvt_pk + single b64 write).
// ---------------------------------------------------------------------------
template<int BM>
__global__ __launch_bounds__(256)
void gemm_bt_kernel(const ushort* __restrict__ A, const ushort* __restrict__ BT,
                    const float* __restrict__ bias, void* __restrict__ out,
                    ushort* __restrict__ vtb,
                    int M, int N, int K, int mode)
{
    constexpr int MI = BM / 32;          // acc row-frags per wave (2x2 wave grid)
    __shared__ ushort As[2][BM * 32];
    __shared__ ushort Bs[2][128 * 32];

    const int t = threadIdx.x;
    const int wave = t >> 6, lane = t & 63;
    const int quad = lane >> 4, l15 = lane & 15;
    const int row0 = blockIdx.y * BM, col0 = blockIdx.x * 128;
    const int wm = (wave >> 1) * (BM / 2), wn = (wave & 1) * 64;

    const int sr = lane >> 2;         // row within a 16-row staging group
    const int sc = (lane & 3) * 8;    // ushort offset (16B chunks)
    const int ra = wave * (BM / 4);   // A rows staged by this wave
    const int rb = wave * 32;         // B rows staged by this wave

    floatx4 acc[MI][4];
#pragma unroll
    for (int i = 0; i < MI; ++i)
#pragma unroll
        for (int j = 0; j < 4; ++j) acc[i][j] = (floatx4){0.f, 0.f, 0.f, 0.f};

#pragma unroll
    for (int ii = 0; ii < BM / 64; ++ii)
        gload_lds16(A + (size_t)(row0 + ra + ii * 16 + sr) * K + sc, &As[0][(ra + ii * 16) * 32]);
    gload_lds16(BT + (size_t)(col0 + rb      + sr) * K + sc, &Bs[0][ rb       * 32]);
    gload_lds16(BT + (size_t)(col0 + rb + 16 + sr) * K + sc, &Bs[0][(rb + 16) * 32]);

    const int nk = K >> 5;
    for (int ki = 0; ki < nk; ++ki) {
        __syncthreads();   // buf[ki&1] staged; all waves done reading buf[(ki+1)&1]
        if (ki + 1 < nk) {
            const int kn = (ki + 1) << 5;
            const int b = (ki + 1) & 1;
#pragma unroll
            for (int ii = 0; ii < BM / 64; ++ii)
                gload_lds16(A + (size_t)(row0 + ra + ii * 16 + sr) * K + kn + sc, &As[b][(ra + ii * 16) * 32]);
            gload_lds16(BT + (size_t)(col0 + rb      + sr) * K + kn + sc, &Bs[b][ rb       * 32]);
            gload_lds16(BT + (size_t)(col0 + rb + 16 + sr) * K + kn + sc, &Bs[b][(rb + 16) * 32]);
        }
        const ushort* as = As[ki & 1];
        const ushort* bs = Bs[ki & 1];

        short8 af[MI], bfr[4];
#pragma unroll
        for (int i = 0; i < MI; ++i)
            af[i] = *(const short8*)&as[(wm + i * 16 + l15) * 32 + quad * 8];
#pragma unroll
        for (int j = 0; j < 4; ++j)
            bfr[j] = *(const short8*)&bs[(wn + j * 16 + l15) * 32 + quad * 8];
#pragma unroll
        for (int i = 0; i < MI; ++i)
#pragma unroll
            for (int j = 0; j < 4; ++j)
                acc[i][j] = __builtin_amdgcn_mfma_f32_16x16x32_bf16(af[i], bfr[j], acc[i][j], 0, 0, 0);
    }

    if (mode == 0) {
        float* outf = (float*)out;
#pragma unroll
        for (int j = 0; j < 4; ++j) {
            int col = col0 + wn + j * 16 + l15;
            float bb = bias[col];
#pragma unroll
            for (int i = 0; i < MI; ++i) {
                int rowb = row0 + wm + i * 16 + quad * 4;
#pragma unroll
                for (int r = 0; r < 4; ++r)
                    outf[(size_t)(rowb + r) * N + col] = acc[i][j][r] + bb;
            }
        }
    } else {
        ushort* outb = (ushort*)out;
#pragma unroll
        for (int j = 0; j < 4; ++j) {
            int col = col0 + wn + j * 16 + l15;
            float bb = bias[col];
            int part = col >> 10, hh = (col >> 6) & 15, d = col & 63;
            if (part < 2) {        // Q,K frag-order: half/quad_k/elem from d
                int half = d >> 5, qk = (d & 31) >> 3, elem = d & 7;
                ushort* base = outb + (size_t)(part * NHEAD + hh) * (NTOK * HDIM);
#pragma unroll
                for (int i = 0; i < MI; ++i) {
                    int rowb = row0 + wm + i * 16 + quad * 4;
#pragma unroll
                    for (int r = 0; r < 4; ++r) {
                        int tok = rowb + r;
                        int tile = tok >> 6, kk = tok & 63;
                        int nt = kk >> 4, lk = kk & 15;
                        base[(size_t)tile * 4096 + ((nt * 2 + half) * 64 + qk * 16 + lk) * 8 + elem]
                            = f2bf(acc[i][j][r] + bb);
                    }
                }
            } else {               // V frag-order with PERMUTED key slots (R7)
                int dt = d >> 4, lv = d & 15;
                ushort* base = vtb + (size_t)hh * (NTOK * HDIM);
#pragma unroll
                for (int i = 0; i < MI; ++i) {
                    int rowb = row0 + wm + i * 16 + quad * 4;
                    int tile = rowb >> 6, kk = rowb & 63;
                    int bslot = ((kk & 15) << 2) | (kk >> 4);   // g(kk); g(kk+r)=g(kk)+4r
#pragma unroll
                    for (int r = 0; r < 4; ++r) {
                        int s = bslot + 4 * r;
                        int off = ((dt * 2 + (s >> 5)) * 64 + ((s >> 3) & 3) * 16 + lv) * 8 + (s & 7);
                        base[(size_t)tile * 4096 + off] = f2bf(acc[i][j][r] + bb);
                    }
                }
            }
        }
    }
}

// ---------------------------------------------------------------------------
// Split-K MFMA flash attention on FRAGMENT-ORDER Q/K/V (R3-R7).
// R7: P stored in key-PERMUTED order k' = g(key) = (key&15)*4 + (key>>4)
// matching V's permuted slots (both operands of PV permuted by the same g ->
// contraction unchanged). Each lane's 4 P values land in 4 consecutive
// ushorts: 2x v_cvt_pk_bf16_f32 + one b64 LDS write replaces 16 scalar-RNE
// ops + 4 scalar writes per row. s_setprio(1) around MFMA clusters (m191:
// attn +4-7%; NOT applied to GEMM, m190 null/negative).
// ---------------------------------------------------------------------------
__global__ __launch_bounds__(512, 4)
void attn_tile_kernel(const ushort* __restrict__ qkvb,   // frag-order Q,K
                      const ushort* __restrict__ vTb,    // frag-order V (permuted slots)
                      const int* __restrict__ frame_ids,
                      const u64* __restrict__ hubmask,   // [NTOK/64]
                      const int* __restrict__ adj,
                      const float* __restrict__ frame_bias,
                      ushort* __restrict__ attnb)        // [N][C] bf16
{
    __shared__ ushort Ps[8][16 * 72];    // per-wave P strip (wave-private), k'-order
    __shared__ float  Om[4][64][21];     // merge: [wq][lane][16 O + 4 l], pad->21

    const int t = threadIdx.x;
    const int wave = t >> 6, lane = t & 63;
    const int wq = wave & 3, wk = wave >> 2;    // q sub-tile, key-list half
    const int quad = lane >> 4, l15 = lane & 15;
    const int b = blockIdx.x;
    const int h = b & 15, q0 = (b >> 4) * 64;   // XCD-locking swizzle

    const ushort* Qh = qkvb + (size_t)h * (NTOK * HDIM);
    const ushort* Kh = qkvb + (size_t)(NHEAD + h) * (NTOK * HDIM);
    const ushort* Vh = vTb + (size_t)h * (NTOK * HDIM);

    // Q A-frags (frag-order: one coalesced 1KB read each)
    const ushort* qt = Qh + (size_t)(q0 >> 6) * 4096;
    short8 aq0 = *(const short8*)(qt + ((wq * 2 + 0) * 64 + lane) * 8);
    short8 aq1 = *(const short8*)(qt + ((wq * 2 + 1) * 64 + lane) * 8);

    // packed visible-frame list (uniform)
    const int fq = frame_ids[q0];
    unsigned vpack = 0; int nv = 0;
#pragma unroll
    for (int f = 0; f < NFRM; ++f)
        if (adj[fq * NFRM + f]) { vpack |= (unsigned)f << (3 * nv); ++nv; }

    const u64 hmq = hubmask[q0 >> 6];
    int qh[4];
#pragma unroll
    for (int r = 0; r < 4; ++r) qh[r] = (int)((hmq >> (wq * 16 + quad * 4 + r)) & 1);

    float lpart[4] = {0.f, 0.f, 0.f, 0.f};
    floatx4 oacc[4];
#pragma unroll
    for (int dt = 0; dt < 4; ++dt) oacc[dt] = (floatx4){0.f, 0.f, 0.f, 0.f};

    const float C1 = 0.18033688011112042f;   // 0.125 * log2(e)
    const float L2E = 1.4426950408889634f;

    // this wave's tiles: vt = wk, wk+2, wk+4, ... (nv*2 of them; nv >= 1)
    const int nmine = nv * 2;
    int vt = wk;
    for (int j = 0; j < nmine; ++j, vt += 2) {
        const int fj = (int)((vpack >> (3 * (vt >> 2))) & 7u);
        const int k0 = fj * FTOK + (vt & 3) * 64;
        const float fbl = frame_bias[fq * NFRM + fj] * L2E;
        const bool same = (fj == fq);
        const u64 hmk = hubmask[k0 >> 6];

        // batched coalesced frag loads: K first, then V (counted vmcnt =>
        // QK waits only on K; V stays in flight under softmax)
        const ushort* kt = Kh + (size_t)(k0 >> 6) * 4096;
        const ushort* vtp = Vh + (size_t)(k0 >> 6) * 4096;
        short8 kf[8], vf[8];
#pragma unroll
        for (int idx = 0; idx < 8; ++idx)
            kf[idx] = *(const short8*)(kt + (idx * 64 + lane) * 8);
#pragma unroll
        for (int idx = 0; idx < 8; ++idx)
            vf[idx] = *(const short8*)(vtp + (idx * 64 + lane) * 8);

        // S strip [16 q][64 keys] = Q @ K^T
        floatx4 s[4];
#pragma unroll
        for (int nt = 0; nt < 4; ++nt)
            s[nt] = (floatx4){0.f, 0.f, 0.f, 0.f};
        __builtin_amdgcn_s_setprio(1);
#pragma unroll
        for (int nt = 0; nt < 4; ++nt) {
            s[nt] = __builtin_amdgcn_mfma_f32_16x16x32_bf16(aq0, kf[2*nt],     s[nt], 0, 0, 0);
            s[nt] = __builtin_amdgcn_mfma_f32_16x16x32_bf16(aq1, kf[2*nt + 1], s[nt], 0, 0, 0);
        }
        __builtin_amdgcn_s_setprio(0);

        // per-tile {0,1} mask floats (hoisted): allow = same || (!qh && !kh)
        float mkf[4];
#pragma unroll
        for (int nt = 0; nt < 4; ++nt) {
            int kb = (int)(((unsigned)(hmk >> (nt * 16)) >> l15) & 1u);
            mkf[nt] = (same || !kb) ? 1.f : 0.f;
        }
        float mrf[4];
#pragma unroll
        for (int r = 0; r < 4; ++r) mrf[r] = (same || !qh[r]) ? 1.f : 0.f;

        // p = exp2(fma(s, C1, fbl)) * mkf * mrf; pack -> k'-order LDS strip:
        // lane's keys nt*16+l15 -> k' = l15*4+nt = 4 consecutive ushorts.
#pragma unroll
        for (int r = 0; r < 4; ++r) {
            float pv[4];
#pragma unroll
            for (int nt = 0; nt < 4; ++nt) {
                float e = __builtin_amdgcn_exp2f(fmaf(s[nt][r], C1, fbl));
                pv[nt] = e * mkf[nt] * mrf[r];
            }
            lpart[r] += (pv[0] + pv[1]) + (pv[2] + pv[3]);
            uint2 pk;
            pk.x = cvt_pk_bf16(pv[0], pv[1]);
            pk.y = cvt_pk_bf16(pv[2], pv[3]);
            *(uint2*)&Ps[wave][(quad * 4 + r) * 72 + l15 * 4] = pk;
        }

        // O strip += P @ V  (both operands in k'-space; V frags in flight)
        short8 ap0 = *(const short8*)&Ps[wave][l15 * 72 + quad * 8];
        short8 ap1 = *(const short8*)&Ps[wave][l15 * 72 + 32 + quad * 8];
        __builtin_amdgcn_s_setprio(1);
#pragma unroll
        for (int dt = 0; dt < 4; ++dt) {
            oacc[dt] = __builtin_amdgcn_mfma_f32_16x16x32_bf16(ap0, vf[2*dt],     oacc[dt], 0, 0, 0);
            oacc[dt] = __builtin_amdgcn_mfma_f32_16x16x32_bf16(ap1, vf[2*dt + 1], oacc[dt], 0, 0, 0);
        }
        __builtin_amdgcn_s_setprio(0);
    }

    // merge the two key-half partials (plain sums — no-max softmax)
    if (wk == 1) {
#pragma unroll
        for (int dt = 0; dt < 4; ++dt)
#pragma unroll
            for (int r = 0; r < 4; ++r) Om[wq][lane][dt * 4 + r] = oacc[dt][r];
#pragma unroll
        for (int r = 0; r < 4; ++r) Om[wq][lane][16 + r] = lpart[r];
    }
    __syncthreads();
    if (wk == 1) return;

#pragma unroll
    for (int dt = 0; dt < 4; ++dt)
#pragma unroll
        for (int r = 0; r < 4; ++r) oacc[dt][r] += Om[wq][lane][dt * 4 + r];
#pragma unroll
    for (int r = 0; r < 4; ++r) lpart[r] += Om[wq][lane][16 + r];

    // final row-sum reduction across the 16 l15 lanes
    float linv[4];
#pragma unroll
    for (int r = 0; r < 4; ++r) {
        float ls = lpart[r];
        ls += __shfl_xor(ls, 1);
        ls += __shfl_xor(ls, 2);
        ls += __shfl_xor(ls, 4);
        ls += __shfl_xor(ls, 8);
        linv[r] = 1.0f / ls;
    }

    // epilogue: attnb[row][h*64 + d] bf16
#pragma unroll
    for (int dt = 0; dt < 4; ++dt) {
        int col = h * HDIM + dt * 16 + l15;
#pragma unroll
        for (int r = 0; r < 4; ++r) {
            int row = q0 + wq * 16 + quad * 4 + r;
            attnb[(size_t)row * CDIM + col] = f2bf(oacc[dt][r] * linv[r]);
        }
    }
}

// ---------------------------------------------------------------------------
extern "C" void kernel_launch(void* const* d_in, const int* in_sizes, int n_in,
                              void* d_out, int out_size, void* d_ws, size_t ws_size,
                              hipStream_t stream)
{
    const float* x          = (const float*)d_in[0];
    const int*   frame_ids  = (const int*)d_in[1];
    const int*   is_hub     = (const int*)d_in[2];
    const int*   adj        = (const int*)d_in[3];
    const float* frame_bias = (const float*)d_in[4];
    const float* Wqkv       = (const float*)d_in[5];
    const float* bqkv       = (const float*)d_in[6];
    const float* Wproj      = (const float*)d_in[7];
    const float* bproj      = (const float*)d_in[8];
    float* out = (float*)d_out;

    // workspace layout (ushort units)
    ushort* xb     = (ushort*)d_ws;            // 2048*1024
    ushort* wqkvT  = xb     + 2097152;         // 3072*1024
    ushort* wprojT = wqkvT  + 3145728;         // 1024*1024
    ushort* qkvb   = wprojT + 1048576;         // [2][H][N][D] used (frag-order)
    ushort* vTb    = qkvb   + 6291456;         // 16*64*2048 (frag-order, permuted)
    ushort* attnb  = vTb    + 2097152;         // 2048*1024
    u64*    hubmask = (u64*)(attnb + 2097152); // 32 x u64

    prep_kernel<<<dim3(3073), dim3(256), 0, stream>>>(
        x, xb, Wqkv, wqkvT, Wproj, wprojT, is_hub, hubmask);

    // QKV: [2048,1024] @ [1024,3072]; Q,K,V -> frag-order layouts. BM=128.
    gemm_bt_kernel<128><<<dim3(3 * CDIM / 128, NTOK / 128), dim3(256), 0, stream>>>(
        xb, wqkvT, bqkv, qkvb, vTb, NTOK, 3 * CDIM, CDIM, 1);

    attn_tile_kernel<<<dim3(512), dim3(512), 0, stream>>>(
        qkvb, vTb, frame_ids, hubmask, adj, frame_bias, attnb);

    // proj: [2048,1024] @ [1024,1024] -> fp32 d_out. BM=64 (256 blocks, 1/CU).
    gemm_bt_kernel<64><<<dim3(CDIM / 128, NTOK / 64), dim3(256), 0, stream>>>(
        attnb, wprojT, bproj, out, nullptr, NTOK, CDIM, CDIM, 0);
}

// Round 9
// 139.180 us; speedup vs baseline: 1.3131x; 1.0193x over previous
//
#include <hip/hip_runtime.h>

#define NTOK 2048
#define CDIM 1024
#define NHEAD 16
#define HDIM 64
#define NFRM 8
#define FTOK 256

typedef unsigned short ushort;
typedef unsigned long long u64;
typedef __attribute__((ext_vector_type(8))) short short8;     // 8 bf16 = 4 VGPRs (MFMA A/B frag)
typedef __attribute__((ext_vector_type(8))) ushort ushort8;
typedef __attribute__((ext_vector_type(4))) ushort ushort4v;
typedef __attribute__((ext_vector_type(4))) float floatx4;    // MFMA C/D frag

__device__ __forceinline__ ushort f2bf(float f) {
    unsigned int u = __float_as_uint(f);
    return (ushort)((u + 0x7fffu + ((u >> 16) & 1u)) >> 16);   // RNE
}

// packed f32x2 -> bf16x2 (RNE, identical to f2bf); no builtin on gfx950 (m240)
__device__ __forceinline__ unsigned int cvt_pk_bf16(float lo, float hi) {
    unsigned int r;
    asm volatile("v_cvt_pk_bf16_f32 %0, %1, %2" : "=v"(r) : "v"(lo), "v"(hi));
    return r;
}

// async global->LDS, 16B per lane; LDS dest = wave-uniform base + lane*16
__device__ __forceinline__ void gload_lds16(const void* g, void* l) {
    __builtin_amdgcn_global_load_lds(
        (const __attribute__((address_space(1))) unsigned int*)(uintptr_t)g,
        (__attribute__((address_space(3))) unsigned int*)(unsigned int)(uintptr_t)l,
        16, 0, 0);
}

// A frag-order index (R8): token tok, channel c ->
//   ((tok>>6)*32 + (c>>5)) * 2048 + (((tok&63)>>4)*4 + ((c>>3)&3))*128
//   + (tok&15)*8 + (c&7)
// so a wave's 16x16x32 A-frag load is base + i*512 + lane*8: 1KB coalesced.

// ---------------------------------------------------------------------------
// Fused prep: [0,2048) x fp32->bf16 FRAG-ORDER ; [2048,2816) Wqkv^T ;
// [2816,3072) Wproj^T ; [3072] hub bitmask
// ---------------------------------------------------------------------------
__global__ __launch_bounds__(256)
void prep_kernel(const float* __restrict__ x, ushort* __restrict__ xb,
                 const float* __restrict__ Wqkv, ushort* __restrict__ wqkvT,
                 const float* __restrict__ Wproj, ushort* __restrict__ wprojT,
                 const int* __restrict__ is_hub, u64* __restrict__ hubmask)
{
    __shared__ ushort LT[64][72];   // [n][k]
    const int b = blockIdx.x, t = threadIdx.x;

    if (b < 2048) {                 // convx -> frag-order xb
        int i = b * 256 + t;
        int tok = i >> 8, c0 = (i & 255) * 4;
        float4 f = ((const float4*)x)[i];
        ushort4v o = { f2bf(f.x), f2bf(f.y), f2bf(f.z), f2bf(f.w) };
        size_t idx = ((size_t)((tok >> 6) * 32 + (c0 >> 5)) << 11)
                   + ((((tok & 63) >> 4) * 4 + ((c0 >> 3) & 3)) << 7)
                   + ((tok & 15) << 3) + (c0 & 7);
        *(ushort4v*)&xb[idx] = o;
        return;
    }
    if (b >= 3072) {                // hub bitmask: 32 tiles of 64 tokens
        if (t < NTOK / 64) {
            u64 m = 0;
            for (int j = 0; j < 64; ++j)
                m |= (u64)(is_hub[t * 64 + j] != 0) << j;
            hubmask[t] = m;
        }
        return;
    }

    const float* W; ushort* WT; int K, N, n0, k0;
    if (b < 2816) { int idx = b - 2048; W = Wqkv;  WT = wqkvT;  K = 1024; N = 3072;
                    n0 = (idx % 48) * 64; k0 = (idx / 48) * 64; }
    else          { int idx = b - 2816; W = Wproj; WT = wprojT; K = 1024; N = 1024;
                    n0 = (idx & 15) * 64; k0 = (idx >> 4) * 64; }

    const int kr = t >> 4, nc = t & 15;
#pragma unroll
    for (int i = 0; i < 4; ++i) {
        int k = kr + i * 16;
        float4 w4 = *(const float4*)(W + (size_t)(k0 + k) * N + n0 + nc * 4);
        LT[nc*4+0][k] = f2bf(w4.x);
        LT[nc*4+1][k] = f2bf(w4.y);
        LT[nc*4+2][k] = f2bf(w4.z);
        LT[nc*4+3][k] = f2bf(w4.w);
    }
    __syncthreads();
    const int n = t >> 2;
#pragma unroll
    for (int half = 0; half < 2; ++half) {
        int kc = (t & 3) + 4 * half;
        ushort8 v = *(const ushort8*)&LT[n][kc * 8];
        *(ushort8*)(WT + (size_t)(n0 + n) * K + k0 + kc * 8) = v;
    }
}

// ---------------------------------------------------------------------------
// bf16 MFMA GEMM, R8 structure: C = Afrag[M,K] @ BT[N,K]^T + bias.
//  - A read DIRECT from global in frag-order (1KB coalesced, L2-hit, next
//    phase prefetched into regs before the MFMA cluster -> flies across the
//    barrier drain). No A LDS, no A staging.
//  - B staged to LDS in BK=64 phases via global_load_lds with SOURCE-XOR
//    swizzle (rule #21): chunk16 c at col-row r sourced from c^(r&7); reader
//    XORs the same -> ds_read_b128 2-way banked (was 8-way at stride 64B).
//  - 16 barrier phases instead of 32 -> half the vmcnt(0) drain stalls,
//    2x MFMA per phase (32) to cover the prefetch latency.
// mode 0: fp32 store row-major [M][N]; mode 1: QKV scatter (frag-order Q,K;
// key-permuted V for attn's cvt_pk path, R7).
// ---------------------------------------------------------------------------
template<int BM>
__global__ __launch_bounds__(256)
void gemm_bt_kernel(const ushort* __restrict__ Afrag, const ushort* __restrict__ BT,
                    const float* __restrict__ bias, void* __restrict__ out,
                    ushort* __restrict__ vtb,
                    int M, int N, int K, int mode)
{
    constexpr int MI = BM / 32;          // acc row-frags per wave (2x2 wave grid)
    __shared__ ushort Bs[2][128 * 64];   // [col][64k], source-XOR-swizzled

    const int t = threadIdx.x;
    const int wave = t >> 6, lane = t & 63;
    const int quad = lane >> 4, l15 = lane & 15;
    const int row0 = blockIdx.y * BM, col0 = blockIdx.x * 128;
    const int wm = (wave >> 1) * (BM / 2), wn = (wave & 1) * 64;

    // B staging: wave covers cols rb..rb+32; lane -> col-row lane>>3, chunk lane&7
    const int rb = wave * 32;
    const int srb = lane >> 3;
    const int scb = (((lane & 7) ^ (srb & 7)) << 3);   // source chunk XOR-swizzle

    // A frag-order bases
    const int absRow = row0 + wm;
    const int rowtile = absRow >> 6;
    const int ibase = (absRow & 63) >> 4;              // 0 (BM=128) or 0/2 (BM=64)
    const ushort* Abase = Afrag + ((size_t)rowtile * 32 << 11) + lane * 8;

    floatx4 acc[MI][4];
#pragma unroll
    for (int i = 0; i < MI; ++i)
#pragma unroll
        for (int j = 0; j < 4; ++j) acc[i][j] = (floatx4){0.f, 0.f, 0.f, 0.f};

    const int NPH = K >> 6;   // 16 phases of 64 k
    short8 a0[MI], a1[MI], an0[MI], an1[MI];

    // prologue: stage B phase 0; load A phase 0 (2 ksteps)
#pragma unroll
    for (int ii = 0; ii < 4; ++ii)
        gload_lds16(BT + (size_t)(col0 + rb + ii * 8 + srb) * K + scb,
                    &Bs[0][(rb + ii * 8) * 64]);
#pragma unroll
    for (int i = 0; i < MI; ++i) {
        a0[i] = *(const short8*)(Abase + ((size_t)0 << 11) + ((ibase + i) << 9));
        a1[i] = *(const short8*)(Abase + ((size_t)1 << 11) + ((ibase + i) << 9));
    }

    for (int p = 0; p < NPH; ++p) {
        __syncthreads();   // drains B(p) DMA + A(p) reg loads
        if (p + 1 < NPH) {
            const int nb = (p + 1) & 1;
#pragma unroll
            for (int ii = 0; ii < 4; ++ii)
                gload_lds16(BT + (size_t)(col0 + rb + ii * 8 + srb) * K + (p + 1) * 64 + scb,
                            &Bs[nb][(rb + ii * 8) * 64]);
#pragma unroll
            for (int i = 0; i < MI; ++i) {
                an0[i] = *(const short8*)(Abase + ((size_t)(2 * p + 2) << 11) + ((ibase + i) << 9));
                an1[i] = *(const short8*)(Abase + ((size_t)(2 * p + 3) << 11) + ((ibase + i) << 9));
            }
        }
        const ushort* bs = Bs[p & 1];
        const int swz = (l15 & 7) << 3;

        short8 bfr[4];
#pragma unroll
        for (int j = 0; j < 4; ++j)
            bfr[j] = *(const short8*)&bs[(((wn + j * 16 + l15) * 64) + quad * 8) ^ swz];
#pragma unroll
        for (int i = 0; i < MI; ++i)
#pragma unroll
            for (int j = 0; j < 4; ++j)
                acc[i][j] = __builtin_amdgcn_mfma_f32_16x16x32_bf16(a0[i], bfr[j], acc[i][j], 0, 0, 0);
#pragma unroll
        for (int j = 0; j < 4; ++j)
            bfr[j] = *(const short8*)&bs[(((wn + j * 16 + l15) * 64) + 32 + quad * 8) ^ swz];
#pragma unroll
        for (int i = 0; i < MI; ++i)
#pragma unroll
            for (int j = 0; j < 4; ++j)
                acc[i][j] = __builtin_amdgcn_mfma_f32_16x16x32_bf16(a1[i], bfr[j], acc[i][j], 0, 0, 0);

#pragma unroll
        for (int i = 0; i < MI; ++i) { a0[i] = an0[i]; a1[i] = an1[i]; }
    }

    if (mode == 0) {
        float* outf = (float*)out;
#pragma unroll
        for (int j = 0; j < 4; ++j) {
            int col = col0 + wn + j * 16 + l15;
            float bb = bias[col];
#pragma unroll
            for (int i = 0; i < MI; ++i) {
                int rowb = row0 + wm + i * 16 + quad * 4;
#pragma unroll
                for (int r = 0; r < 4; ++r)
                    outf[(size_t)(rowb + r) * N + col] = acc[i][j][r] + bb;
            }
        }
    } else {
        ushort* outb = (ushort*)out;
#pragma unroll
        for (int j = 0; j < 4; ++j) {
            int col = col0 + wn + j * 16 + l15;
            float bb = bias[col];
            int part = col >> 10, hh = (col >> 6) & 15, d = col & 63;
            if (part < 2) {        // Q,K frag-order: half/quad_k/elem from d
                int half = d >> 5, qk = (d & 31) >> 3, elem = d & 7;
                ushort* base = outb + (size_t)(part * NHEAD + hh) * (NTOK * HDIM);
#pragma unroll
                for (int i = 0; i < MI; ++i) {
                    int rowb = row0 + wm + i * 16 + quad * 4;
#pragma unroll
                    for (int r = 0; r < 4; ++r) {
                        int tok = rowb + r;
                        int tile = tok >> 6, kk = tok & 63;
                        int nt = kk >> 4, lk = kk & 15;
                        base[(size_t)tile * 4096 + ((nt * 2 + half) * 64 + qk * 16 + lk) * 8 + elem]
                            = f2bf(acc[i][j][r] + bb);
                    }
                }
            } else {               // V frag-order with PERMUTED key slots (R7)
                int dt = d >> 4, lv = d & 15;
                ushort* base = vtb + (size_t)hh * (NTOK * HDIM);
#pragma unroll
                for (int i = 0; i < MI; ++i) {
                    int rowb = row0 + wm + i * 16 + quad * 4;
                    int tile = rowb >> 6, kk = rowb & 63;
                    int bslot = ((kk & 15) << 2) | (kk >> 4);   // g(kk); g(kk+r)=g(kk)+4r
#pragma unroll
                    for (int r = 0; r < 4; ++r) {
                        int s = bslot + 4 * r;
                        int off = ((dt * 2 + (s >> 5)) * 64 + ((s >> 3) & 3) * 16 + lv) * 8 + (s & 7);
                        base[(size_t)tile * 4096 + off] = f2bf(acc[i][j][r] + bb);
                    }
                }
            }
        }
    }
}

// ---------------------------------------------------------------------------
// Split-K MFMA flash attention on FRAGMENT-ORDER Q/K/V (R3-R7). R8: epilogue
// writes attnb in frag-order so proj's A-side reads it direct-from-L2.
// ---------------------------------------------------------------------------
__global__ __launch_bounds__(512, 4)
void attn_tile_kernel(const ushort* __restrict__ qkvb,   // frag-order Q,K
                      const ushort* __restrict__ vTb,    // frag-order V (permuted slots)
                      const int* __restrict__ frame_ids,
                      const u64* __restrict__ hubmask,   // [NTOK/64]
                      const int* __restrict__ adj,
                      const float* __restrict__ frame_bias,
                      ushort* __restrict__ attnb)        // frag-order [N][C]
{
    __shared__ ushort Ps[8][16 * 72];    // per-wave P strip (wave-private), k'-order
    __shared__ float  Om[4][64][21];     // merge: [wq][lane][16 O + 4 l], pad->21

    const int t = threadIdx.x;
    const int wave = t >> 6, lane = t & 63;
    const int wq = wave & 3, wk = wave >> 2;    // q sub-tile, key-list half
    const int quad = lane >> 4, l15 = lane & 15;
    const int b = blockIdx.x;
    const int h = b & 15, q0 = (b >> 4) * 64;   // XCD-locking swizzle

    const ushort* Qh = qkvb + (size_t)h * (NTOK * HDIM);
    const ushort* Kh = qkvb + (size_t)(NHEAD + h) * (NTOK * HDIM);
    const ushort* Vh = vTb + (size_t)h * (NTOK * HDIM);

    // Q A-frags (frag-order: one coalesced 1KB read each)
    const ushort* qt = Qh + (size_t)(q0 >> 6) * 4096;
    short8 aq0 = *(const short8*)(qt + ((wq * 2 + 0) * 64 + lane) * 8);
    short8 aq1 = *(const short8*)(qt + ((wq * 2 + 1) * 64 + lane) * 8);

    // packed visible-frame list (uniform)
    const int fq = frame_ids[q0];
    unsigned vpack = 0; int nv = 0;
#pragma unroll
    for (int f = 0; f < NFRM; ++f)
        if (adj[fq * NFRM + f]) { vpack |= (unsigned)f << (3 * nv); ++nv; }

    const u64 hmq = hubmask[q0 >> 6];
    int qh[4];
#pragma unroll
    for (int r = 0; r < 4; ++r) qh[r] = (int)((hmq >> (wq * 16 + quad * 4 + r)) & 1);

    float lpart[4] = {0.f, 0.f, 0.f, 0.f};
    floatx4 oacc[4];
#pragma unroll
    for (int dt = 0; dt < 4; ++dt) oacc[dt] = (floatx4){0.f, 0.f, 0.f, 0.f};

    const float C1 = 0.18033688011112042f;   // 0.125 * log2(e)
    const float L2E = 1.4426950408889634f;

    // this wave's tiles: vt = wk, wk+2, wk+4, ... (nv*2 of them; nv >= 1)
    const int nmine = nv * 2;
    int vt = wk;
    for (int j = 0; j < nmine; ++j, vt += 2) {
        const int fj = (int)((vpack >> (3 * (vt >> 2))) & 7u);
        const int k0 = fj * FTOK + (vt & 3) * 64;
        const float fbl = frame_bias[fq * NFRM + fj] * L2E;
        const bool same = (fj == fq);
        const u64 hmk = hubmask[k0 >> 6];

        // batched coalesced frag loads: K first, then V (counted vmcnt =>
        // QK waits only on K; V stays in flight under softmax)
        const ushort* kt = Kh + (size_t)(k0 >> 6) * 4096;
        const ushort* vtp = Vh + (size_t)(k0 >> 6) * 4096;
        short8 kf[8], vf[8];
#pragma unroll
        for (int idx = 0; idx < 8; ++idx)
            kf[idx] = *(const short8*)(kt + (idx * 64 + lane) * 8);
#pragma unroll
        for (int idx = 0; idx < 8; ++idx)
            vf[idx] = *(const short8*)(vtp + (idx * 64 + lane) * 8);

        // S strip [16 q][64 keys] = Q @ K^T
        floatx4 s[4];
#pragma unroll
        for (int nt = 0; nt < 4; ++nt)
            s[nt] = (floatx4){0.f, 0.f, 0.f, 0.f};
        __builtin_amdgcn_s_setprio(1);
#pragma unroll
        for (int nt = 0; nt < 4; ++nt) {
            s[nt] = __builtin_amdgcn_mfma_f32_16x16x32_bf16(aq0, kf[2*nt],     s[nt], 0, 0, 0);
            s[nt] = __builtin_amdgcn_mfma_f32_16x16x32_bf16(aq1, kf[2*nt + 1], s[nt], 0, 0, 0);
        }
        __builtin_amdgcn_s_setprio(0);

        // per-tile {0,1} mask floats (hoisted): allow = same || (!qh && !kh)
        float mkf[4];
#pragma unroll
        for (int nt = 0; nt < 4; ++nt) {
            int kb = (int)(((unsigned)(hmk >> (nt * 16)) >> l15) & 1u);
            mkf[nt] = (same || !kb) ? 1.f : 0.f;
        }
        float mrf[4];
#pragma unroll
        for (int r = 0; r < 4; ++r) mrf[r] = (same || !qh[r]) ? 1.f : 0.f;

        // p = exp2(fma(s, C1, fbl)) * mkf * mrf; pack -> k'-order LDS strip:
        // lane's keys nt*16+l15 -> k' = l15*4+nt = 4 consecutive ushorts.
#pragma unroll
        for (int r = 0; r < 4; ++r) {
            float pv[4];
#pragma unroll
            for (int nt = 0; nt < 4; ++nt) {
                float e = __builtin_amdgcn_exp2f(fmaf(s[nt][r], C1, fbl));
                pv[nt] = e * mkf[nt] * mrf[r];
            }
            lpart[r] += (pv[0] + pv[1]) + (pv[2] + pv[3]);
            uint2 pk;
            pk.x = cvt_pk_bf16(pv[0], pv[1]);
            pk.y = cvt_pk_bf16(pv[2], pv[3]);
            *(uint2*)&Ps[wave][(quad * 4 + r) * 72 + l15 * 4] = pk;
        }

        // O strip += P @ V  (both operands in k'-space; V frags in flight)
        short8 ap0 = *(const short8*)&Ps[wave][l15 * 72 + quad * 8];
        short8 ap1 = *(const short8*)&Ps[wave][l15 * 72 + 32 + quad * 8];
        __builtin_amdgcn_s_setprio(1);
#pragma unroll
        for (int dt = 0; dt < 4; ++dt) {
            oacc[dt] = __builtin_amdgcn_mfma_f32_16x16x32_bf16(ap0, vf[2*dt],     oacc[dt], 0, 0, 0);
            oacc[dt] = __builtin_amdgcn_mfma_f32_16x16x32_bf16(ap1, vf[2*dt + 1], oacc[dt], 0, 0, 0);
        }
        __builtin_amdgcn_s_setprio(0);
    }

    // merge the two key-half partials (plain sums — no-max softmax)
    if (wk == 1) {
#pragma unroll
        for (int dt = 0; dt < 4; ++dt)
#pragma unroll
            for (int r = 0; r < 4; ++r) Om[wq][lane][dt * 4 + r] = oacc[dt][r];
#pragma unroll
        for (int r = 0; r < 4; ++r) Om[wq][lane][16 + r] = lpart[r];
    }
    __syncthreads();
    if (wk == 1) return;

#pragma unroll
    for (int dt = 0; dt < 4; ++dt)
#pragma unroll
        for (int r = 0; r < 4; ++r) oacc[dt][r] += Om[wq][lane][dt * 4 + r];
#pragma unroll
    for (int r = 0; r < 4; ++r) lpart[r] += Om[wq][lane][16 + r];

    // final row-sum reduction across the 16 l15 lanes
    float linv[4];
#pragma unroll
    for (int r = 0; r < 4; ++r) {
        float ls = lpart[r];
        ls += __shfl_xor(ls, 1);
        ls += __shfl_xor(ls, 2);
        ls += __shfl_xor(ls, 4);
        ls += __shfl_xor(ls, 8);
        linv[r] = 1.0f / ls;
    }

    // epilogue: attnb FRAG-ORDER (R8) so proj reads A direct:
    // row=q0+wq*16+quad*4+r, c=h*64+dt*16+l15 ->
    // ((row>>6)*32 + h*2+(dt>>1))<<11  + ((wq*4 + (dt&1)*2 + (l15>>3))*16
    //  + quad*4 + r)*8 + (l15&7)
    const size_t tbase = ((size_t)(q0 >> 6) * 32) << 11;
#pragma unroll
    for (int dt = 0; dt < 4; ++dt) {
        size_t kbase = tbase + ((size_t)(h * 2 + (dt >> 1)) << 11)
                     + ((wq * 4 + (dt & 1) * 2 + (l15 >> 3)) << 7)
                     + (quad << 5) + (l15 & 7);
#pragma unroll
        for (int r = 0; r < 4; ++r)
            attnb[kbase + r * 8] = f2bf(oacc[dt][r] * linv[r]);
    }
}

// ---------------------------------------------------------------------------
extern "C" void kernel_launch(void* const* d_in, const int* in_sizes, int n_in,
                              void* d_out, int out_size, void* d_ws, size_t ws_size,
                              hipStream_t stream)
{
    const float* x          = (const float*)d_in[0];
    const int*   frame_ids  = (const int*)d_in[1];
    const int*   is_hub     = (const int*)d_in[2];
    const int*   adj        = (const int*)d_in[3];
    const float* frame_bias = (const float*)d_in[4];
    const float* Wqkv       = (const float*)d_in[5];
    const float* bqkv       = (const float*)d_in[6];
    const float* Wproj      = (const float*)d_in[7];
    const float* bproj      = (const float*)d_in[8];
    float* out = (float*)d_out;

    // workspace layout (ushort units)
    ushort* xb     = (ushort*)d_ws;            // 2048*1024 (frag-order)
    ushort* wqkvT  = xb     + 2097152;         // 3072*1024
    ushort* wprojT = wqkvT  + 3145728;         // 1024*1024
    ushort* qkvb   = wprojT + 1048576;         // [2][H][N][D] used (frag-order)
    ushort* vTb    = qkvb   + 6291456;         // 16*64*2048 (frag-order, permuted)
    ushort* attnb  = vTb    + 2097152;         // 2048*1024 (frag-order)
    u64*    hubmask = (u64*)(attnb + 2097152); // 32 x u64

    prep_kernel<<<dim3(3073), dim3(256), 0, stream>>>(
        x, xb, Wqkv, wqkvT, Wproj, wprojT, is_hub, hubmask);

    // QKV: [2048,1024] @ [1024,3072]; Q,K,V -> frag-order layouts. BM=128.
    gemm_bt_kernel<128><<<dim3(3 * CDIM / 128, NTOK / 128), dim3(256), 0, stream>>>(
        xb, wqkvT, bqkv, qkvb, vTb, NTOK, 3 * CDIM, CDIM, 1);

    attn_tile_kernel<<<dim3(512), dim3(512), 0, stream>>>(
        qkvb, vTb, frame_ids, hubmask, adj, frame_bias, attnb);

    // proj: [2048,1024] @ [1024,1024] -> fp32 d_out. BM=64 (256 blocks, 1/CU).
    gemm_bt_kernel<64><<<dim3(CDIM / 128, NTOK / 64), dim3(256), 0, stream>>>(
        attnb, wprojT, bproj, out, nullptr, NTOK, CDIM, CDIM, 0);
}